// Round 11
// baseline (186.042 us; speedup 1.0000x reference)
//
#include <hip/hip_runtime.h>

#define TPB    256
#define VSHIFT 12
#define VBUCK  (1 << VSHIFT)        // 4096 vertices per bucket
#define NBMAX  256                  // max buckets (1e6/4096 = 245); == TPB
#define EPT    16                   // edges/thread/round, partition
#define ROUND  (TPB * EPT)          // 4096 edges/round
#define RPB    2                    // rounds per block
#define PBLK   (ROUND * RPB)        // 8192 edges/block
#define SPLITMAX 4                  // preferred accumulate sub-blocks per bucket
#define ATPB   1024                 // accumulate threads per block

__device__ __forceinline__ unsigned long long pack_pair(int d, float v) {
    return (unsigned long long)(unsigned)d |
           ((unsigned long long)__float_as_uint(v) << 32);
}

// Exclusive scan across TPB threads; also returns block total (uniform).
__device__ __forceinline__ int block_excl_scan(int v, int t, int* wsum, int* total) {
    int s = v;
    #pragma unroll
    for (int d = 1; d < 64; d <<= 1) {
        int u = __shfl_up(s, d);
        if ((t & 63) >= d) s += u;
    }
    if ((t & 63) == 63) wsum[t >> 6] = s;
    __syncthreads();
    int add = 0;
    #pragma unroll
    for (int w = 0; w < TPB / 64; ++w)
        if (w < (t >> 6)) add += wsum[w];
    int tot = wsum[0] + wsum[1] + wsum[2] + wsum[3];
    __syncthreads();                 // wsum safe for reuse
    *total = tot;
    return s + add - v;
}

// Per-partition-block bucket histogram, stored transposed: histp[b][blk].
__global__ void hist_blocks_kernel(const int* __restrict__ dst, long long n_edge,
                                   int nblk, int* __restrict__ histp) {
    __shared__ int h[NBMAX];
    const int t = threadIdx.x;
    h[t] = 0;
    __syncthreads();
    const long long bbase = (long long)blockIdx.x * PBLK;
    const long long bend0 = bbase + PBLK;
    const long long bend  = bend0 < n_edge ? bend0 : n_edge;
    #pragma unroll 4
    for (int j = 0; j < PBLK / TPB / 4; ++j) {
        long long e = bbase + ((long long)j * TPB + t) * 4;
        if (e + 4 <= bend) {
            int4 d = *reinterpret_cast<const int4*>(dst + e);
            atomicAdd(&h[d.x >> VSHIFT], 1);
            atomicAdd(&h[d.y >> VSHIFT], 1);
            atomicAdd(&h[d.z >> VSHIFT], 1);
            atomicAdd(&h[d.w >> VSHIFT], 1);
        } else {
            for (int q = 0; q < 4; ++q) {
                long long ee = e + q;
                if (ee < bend) atomicAdd(&h[dst[ee] >> VSHIFT], 1);
            }
        }
    }
    __syncthreads();
    histp[(size_t)t * nblk + blockIdx.x] = h[t];
}

// One block per bucket: exclusive-scan its row of per-block counts in place;
// write the bucket total.
__global__ void row_scan_kernel(int* __restrict__ histp, int nblk,
                                int* __restrict__ totals) {
    __shared__ int wsum[TPB / 64];
    const int t = threadIdx.x;
    int* row = histp + (size_t)blockIdx.x * nblk;
    int carry = 0;
    for (int base = 0; base < nblk; base += TPB) {
        int v = (base + t < nblk) ? row[base + t] : 0;
        int tot;
        int excl = block_excl_scan(v, t, wsum, &tot);
        if (base + t < nblk) row[base + t] = carry + excl;
        carry += tot;
        __syncthreads();
    }
    if (t == 0) totals[blockIdx.x] = carry;
}

// Exclusive scan of bucket totals -> bucket base offsets (base[NBMAX+1]).
__global__ void base_scan_kernel(const int* __restrict__ totals, int nb,
                                 int* __restrict__ base) {
    __shared__ int wsum[TPB / 64];
    const int t = threadIdx.x;
    int v = (t < nb) ? totals[t] : 0;
    int tot;
    int excl = block_excl_scan(v, t, wsum, &tot);
    base[t] = excl;
    if (t == TPB - 1) base[TPB] = excl + v;
}

// Partition edges into per-bucket pair regions. Offsets fully precomputed.
// Fast path (full blocks): double-buffered register prefetch so next round's
// HBM loads are in flight during this round's LDS phases + flush.
__global__ __launch_bounds__(TPB, 4)
void partition_kernel(const int* __restrict__ dst,
                      const float* __restrict__ ea,
                      long long n_edge, int nblk,
                      const int* __restrict__ histp,
                      const int* __restrict__ base,
                      unsigned long long* __restrict__ pairs) {
    __shared__ unsigned long long stage[ROUND];   // 32 KB, bucket-sorted pairs
    __shared__ int h[NBMAX];      // round histogram
    __shared__ int pos[NBMAX];    // round scatter cursors
    __shared__ int adj[NBMAX];    // gbase - pfx per bucket
    __shared__ int wsum[TPB / 64];

    const int t = threadIdx.x;
    const long long bbase = (long long)blockIdx.x * PBLK;
    int my_gbase = base[t] + histp[(size_t)t * nblk + blockIdx.x];

    if (bbase + PBLK <= n_edge) {
        // ---------- fast path: full block, prefetch double-buffer ----------
        int4   dr[2][EPT / 4];
        float4 vr[2][EPT / 4];
        #pragma unroll
        for (int j = 0; j < EPT / 4; ++j) {
            long long e = bbase + ((long long)j * TPB + t) * 4;
            dr[0][j] = *reinterpret_cast<const int4*>(dst + e);
            vr[0][j] = *reinterpret_cast<const float4*>(ea + e);
        }
        #pragma unroll
        for (int r = 0; r < RPB; ++r) {
            const int cur = r & 1, nxt = cur ^ 1;
            if (r + 1 < RPB) {                    // issue next round's loads NOW
                const long long pb = bbase + (long long)(r + 1) * ROUND;
                #pragma unroll
                for (int j = 0; j < EPT / 4; ++j) {
                    long long e = pb + ((long long)j * TPB + t) * 4;
                    dr[nxt][j] = *reinterpret_cast<const int4*>(dst + e);
                    vr[nxt][j] = *reinterpret_cast<const float4*>(ea + e);
                }
            }
            h[t] = 0;
            __syncthreads();
            #pragma unroll
            for (int j = 0; j < EPT / 4; ++j) {
                atomicAdd(&h[dr[cur][j].x >> VSHIFT], 1);
                atomicAdd(&h[dr[cur][j].y >> VSHIFT], 1);
                atomicAdd(&h[dr[cur][j].z >> VSHIFT], 1);
                atomicAdd(&h[dr[cur][j].w >> VSHIFT], 1);
            }
            __syncthreads();
            int rt;
            int excl = block_excl_scan(h[t], t, wsum, &rt);
            pos[t] = excl;
            adj[t] = my_gbase - excl;
            __syncthreads();
            #pragma unroll
            for (int j = 0; j < EPT / 4; ++j) {
                int   dd[4] = {dr[cur][j].x, dr[cur][j].y, dr[cur][j].z, dr[cur][j].w};
                float vv[4] = {vr[cur][j].x, vr[cur][j].y, vr[cur][j].z, vr[cur][j].w};
                #pragma unroll
                for (int q = 0; q < 4; ++q) {
                    int b = dd[q] >> VSHIFT;
                    int slot = atomicAdd(&pos[b], 1);
                    stage[slot] = pack_pair(dd[q], vv[q]);
                }
            }
            __syncthreads();
            #pragma unroll
            for (int i0 = 0; i0 < ROUND; i0 += TPB) {   // rt == ROUND here
                int i = i0 + t;
                unsigned long long p = stage[i];
                int b = (int)((unsigned)(p & 0xffffffffull) >> VSHIFT);
                pairs[(size_t)(adj[b] + i)] = p;
            }
            my_gbase += h[t];
            // no trailing barrier: next round's post-reset barrier protects
            // stage (rewritten only after 3 barriers) and adj (after 2).
        }
    } else {
        // ---------- guarded tail path (last block only) ----------
        const long long bend = n_edge;
        for (int r = 0; r < RPB; ++r) {
            const long long rbase = bbase + (long long)r * ROUND;
            if (rbase >= bend) break;              // uniform across block
            h[t] = 0;
            __syncthreads();

            int4   dreg[EPT / 4];
            float4 vreg[EPT / 4];
            int    nval[EPT / 4];
            #pragma unroll
            for (int j = 0; j < EPT / 4; ++j) {
                long long e = rbase + ((long long)j * TPB + t) * 4;
                if (e + 4 <= bend) {
                    dreg[j] = *reinterpret_cast<const int4*>(dst + e);
                    vreg[j] = *reinterpret_cast<const float4*>(ea + e);
                    nval[j] = 4;
                } else {
                    int dd[4] = {0, 0, 0, 0};
                    float vv[4] = {0.f, 0.f, 0.f, 0.f};
                    int nv = 0;
                    for (int q = 0; q < 4; ++q) {
                        long long ee = e + q;
                        if (ee < bend) { dd[q] = dst[ee]; vv[q] = ea[ee]; nv = q + 1; }
                    }
                    dreg[j] = make_int4(dd[0], dd[1], dd[2], dd[3]);
                    vreg[j] = make_float4(vv[0], vv[1], vv[2], vv[3]);
                    nval[j] = nv;
                }
                if (nval[j] > 0) atomicAdd(&h[dreg[j].x >> VSHIFT], 1);
                if (nval[j] > 1) atomicAdd(&h[dreg[j].y >> VSHIFT], 1);
                if (nval[j] > 2) atomicAdd(&h[dreg[j].z >> VSHIFT], 1);
                if (nval[j] > 3) atomicAdd(&h[dreg[j].w >> VSHIFT], 1);
            }
            __syncthreads();

            int rt;
            int excl = block_excl_scan(h[t], t, wsum, &rt);
            pos[t] = excl;
            adj[t] = my_gbase - excl;
            __syncthreads();

            #pragma unroll
            for (int j = 0; j < EPT / 4; ++j) {
                int   dd[4] = {dreg[j].x, dreg[j].y, dreg[j].z, dreg[j].w};
                float vv[4] = {vreg[j].x, vreg[j].y, vreg[j].z, vreg[j].w};
                #pragma unroll
                for (int q = 0; q < 4; ++q) {
                    if (q < nval[j]) {
                        int b = dd[q] >> VSHIFT;
                        int slot = atomicAdd(&pos[b], 1);
                        stage[slot] = pack_pair(dd[q], vv[q]);
                    }
                }
            }
            __syncthreads();

            for (int i = t; i < rt; i += TPB) {
                unsigned long long p = stage[i];
                int b = (int)((unsigned)(p & 0xffffffffull) >> VSHIFT);
                pairs[(size_t)(adj[b] + i)] = p;
            }
            __syncthreads();
            my_gbase += h[t];
        }
    }
}

// split blocks per bucket: each accumulates its slice of the bucket's pairs
// into LDS (vectorized, unrolled loads for MLP), writes a partial slab.
__global__ __launch_bounds__(ATPB)
void accum_partial_kernel(const unsigned long long* __restrict__ pairs,
                          const int* __restrict__ base,
                          float* __restrict__ partials, int n_vert, int nb,
                          int split) {
    __shared__ __align__(16) float acc[VBUCK];
    const int b  = blockIdx.x % nb;
    const int sp = blockIdx.x / nb;
    const int t  = threadIdx.x;
    #pragma unroll
    for (int i = t; i < VBUCK; i += ATPB) acc[i] = 0.f;
    __syncthreads();

    const int s = base[b];
    const int e = base[b + 1];
    const long long len = e - s;
    const int i0 = s + (int)((len * sp) / split);
    const int i1 = s + (int)((len * (sp + 1)) / split);
    const int a0 = (i0 + 1) & ~1;          // first even index >= i0
    const int a1 = i1 & ~1;                // last even boundary <= i1

    // odd head / odd tail (at most one pair each)
    if (t == 0 && (i0 & 1) && i0 < i1) {
        unsigned long long p = pairs[i0];
        atomicAdd(&acc[(int)(p & (VBUCK - 1))],
                  __uint_as_float((unsigned)(p >> 32)));
    }
    if (t == 1 && (i1 & 1) && (i1 - 1) >= i0) {
        unsigned long long p = pairs[i1 - 1];
        atomicAdd(&acc[(int)(p & (VBUCK - 1))],
                  __uint_as_float((unsigned)(p >> 32)));
    }

    const int n2 = (a1 - a0) >> 1;         // ulonglong2 elements
    const ulonglong2* pv = reinterpret_cast<const ulonglong2*>(pairs + a0);
    int j = t;
    for (; j + 3 * ATPB < n2; j += 4 * ATPB) {
        ulonglong2 q0 = pv[j];
        ulonglong2 q1 = pv[j + ATPB];
        ulonglong2 q2 = pv[j + 2 * ATPB];
        ulonglong2 q3 = pv[j + 3 * ATPB];
        atomicAdd(&acc[(int)(q0.x & (VBUCK - 1))], __uint_as_float((unsigned)(q0.x >> 32)));
        atomicAdd(&acc[(int)(q0.y & (VBUCK - 1))], __uint_as_float((unsigned)(q0.y >> 32)));
        atomicAdd(&acc[(int)(q1.x & (VBUCK - 1))], __uint_as_float((unsigned)(q1.x >> 32)));
        atomicAdd(&acc[(int)(q1.y & (VBUCK - 1))], __uint_as_float((unsigned)(q1.y >> 32)));
        atomicAdd(&acc[(int)(q2.x & (VBUCK - 1))], __uint_as_float((unsigned)(q2.x >> 32)));
        atomicAdd(&acc[(int)(q2.y & (VBUCK - 1))], __uint_as_float((unsigned)(q2.y >> 32)));
        atomicAdd(&acc[(int)(q3.x & (VBUCK - 1))], __uint_as_float((unsigned)(q3.x >> 32)));
        atomicAdd(&acc[(int)(q3.y & (VBUCK - 1))], __uint_as_float((unsigned)(q3.y >> 32)));
    }
    for (; j < n2; j += ATPB) {
        ulonglong2 q = pv[j];
        atomicAdd(&acc[(int)(q.x & (VBUCK - 1))], __uint_as_float((unsigned)(q.x >> 32)));
        atomicAdd(&acc[(int)(q.y & (VBUCK - 1))], __uint_as_float((unsigned)(q.y >> 32)));
    }
    __syncthreads();

    float* pp = partials + (size_t)sp * n_vert;
    const int vbase = b << VSHIFT;
    if (vbase + VBUCK <= n_vert) {
        reinterpret_cast<float4*>(pp + vbase)[t] =
            reinterpret_cast<const float4*>(acc)[t];
    } else {
        for (int v = t; vbase + v < n_vert; v += ATPB) pp[vbase + v] = acc[v];
    }
}

// Sum split partials + vertex update; 4 vertices/thread, float4 I/O.
__global__ void final_update_kernel(const float* __restrict__ partials,
                                    const float* __restrict__ va,
                                    const float* __restrict__ g,
                                    float* __restrict__ out, int n_vert,
                                    int split) {
    const int gt = blockIdx.x * blockDim.x + threadIdx.x;
    const float w = g[0];
    const int v0 = gt * 4;
    if (v0 + 4 <= n_vert) {
        float4 c = reinterpret_cast<const float4*>(partials)[gt];
        for (int sp = 1; sp < split; ++sp) {
            float4 c2 = reinterpret_cast<const float4*>(
                            partials + (size_t)sp * n_vert)[gt];
            c.x += c2.x; c.y += c2.y; c.z += c2.z; c.w += c2.w;
        }
        float4 f0 = reinterpret_cast<const float4*>(va)[gt * 3 + 0];
        float4 f1 = reinterpret_cast<const float4*>(va)[gt * 3 + 1];
        float4 f2 = reinterpret_cast<const float4*>(va)[gt * 3 + 2];
        float4 o0, o1, o2;
        o0.x = f0.x; o0.y = f0.y; o0.z = f0.z + w * (f0.y - c.x) / f0.x;
        o0.w = f0.w; o1.x = f1.x; o1.y = f1.y + w * (f1.x - c.y) / f0.w;
        o1.z = f1.z; o1.w = f1.w; o2.x = f2.x + w * (f1.w - c.z) / f1.z;
        o2.y = f2.y; o2.z = f2.z; o2.w = f2.w + w * (f2.z - c.w) / f2.y;
        reinterpret_cast<float4*>(out)[gt * 3 + 0] = o0;
        reinterpret_cast<float4*>(out)[gt * 3 + 1] = o1;
        reinterpret_cast<float4*>(out)[gt * 3 + 2] = o2;
    } else {
        for (int i = v0; i < n_vert; ++i) {
            float c = 0.f;
            for (int sp = 0; sp < split; ++sp)
                c += partials[(size_t)sp * n_vert + i];
            float A = va[3 * i], bb = va[3 * i + 1], x = va[3 * i + 2];
            out[3 * i]     = A;
            out[3 * i + 1] = bb;
            out[3 * i + 2] = x + w * (bb - c) / A;
        }
    }
}

// Fused path (used if partials don't fit in ws).
__global__ void accum_update_kernel(const unsigned long long* __restrict__ pairs,
                                    const int* __restrict__ base,
                                    const float* __restrict__ va,
                                    const float* __restrict__ g,
                                    float* __restrict__ out, int n_vert) {
    __shared__ __align__(16) float acc[VBUCK];
    const int b = blockIdx.x;
    const int T = blockDim.x;                  // 1024
    for (int t = threadIdx.x; t < VBUCK; t += T) acc[t] = 0.f;
    __syncthreads();
    const int s = base[b];
    const int e = base[b + 1];
    for (int i = s + threadIdx.x; i < e; i += T) {
        unsigned long long p = pairs[i];
        atomicAdd(&acc[(int)(p & (VBUCK - 1))],
                  __uint_as_float((unsigned)(p >> 32)));
    }
    __syncthreads();

    const float w = g[0];
    const int vbase = b << VSHIFT;
    const int t = threadIdx.x;
    const int v0 = vbase + t * 4;
    if (v0 + 4 <= n_vert) {
        const int gt = v0 >> 2;
        float4 f0 = reinterpret_cast<const float4*>(va)[gt * 3 + 0];
        float4 f1 = reinterpret_cast<const float4*>(va)[gt * 3 + 1];
        float4 f2 = reinterpret_cast<const float4*>(va)[gt * 3 + 2];
        float4 c  = reinterpret_cast<const float4*>(acc)[t];
        float4 o0, o1, o2;
        o0.x = f0.x; o0.y = f0.y; o0.z = f0.z + w * (f0.y - c.x) / f0.x;
        o0.w = f0.w; o1.x = f1.x; o1.y = f1.y + w * (f1.x - c.y) / f0.w;
        o1.z = f1.z; o1.w = f1.w; o2.x = f2.x + w * (f1.w - c.z) / f1.z;
        o2.y = f2.y; o2.z = f2.z; o2.w = f2.w + w * (f2.z - c.w) / f2.y;
        reinterpret_cast<float4*>(out)[gt * 3 + 0] = o0;
        reinterpret_cast<float4*>(out)[gt * 3 + 1] = o1;
        reinterpret_cast<float4*>(out)[gt * 3 + 2] = o2;
    } else {
        for (int i = v0; i < n_vert && i < v0 + 4; ++i) {
            float A = va[3 * i], bb = va[3 * i + 1], x = va[3 * i + 2];
            out[3 * i]     = A;
            out[3 * i + 1] = bb;
            out[3 * i + 2] = x + w * (bb - acc[i - vbase]) / A;
        }
    }
}

// ---- fallback path (insufficient scratch): device-scope atomics ----
__global__ void scatter_add_dev_kernel(const int* __restrict__ dst,
                                       const float* __restrict__ ea,
                                       float* __restrict__ acc, int n_edges4) {
    int i = blockIdx.x * blockDim.x + threadIdx.x;
    const int stride = gridDim.x * blockDim.x;
    for (; i < n_edges4; i += stride) {
        int4   d = reinterpret_cast<const int4*>(dst)[i];
        float4 v = reinterpret_cast<const float4*>(ea)[i];
        atomicAdd(&acc[d.x], v.x);
        atomicAdd(&acc[d.y], v.y);
        atomicAdd(&acc[d.z], v.z);
        atomicAdd(&acc[d.w], v.w);
    }
}

__global__ void update_kernel(const float* __restrict__ va,
                              const float* __restrict__ cbar,
                              const float* __restrict__ g,
                              float* __restrict__ out, int n) {
    int i = blockIdx.x * blockDim.x + threadIdx.x;
    if (i >= n) return;
    float A = va[3 * i], b = va[3 * i + 1], x = va[3 * i + 2];
    out[3 * i]     = A;
    out[3 * i + 1] = b;
    out[3 * i + 2] = x + g[0] * (b - cbar[i]) / A;
}

extern "C" void kernel_launch(void* const* d_in, const int* in_sizes, int n_in,
                              void* d_out, int out_size, void* d_ws, size_t ws_size,
                              hipStream_t stream) {
    const float* vertex_attr = (const float*)d_in[0];
    const int*   edgeij      = (const int*)d_in[1];   // row 0 = dst
    const float* edge_attr   = (const float*)d_in[2];
    const float* g           = (const float*)d_in[3];

    const int       n_vert = in_sizes[0] / 3;
    const long long n_edge = in_sizes[2];
    const int       nb     = (n_vert + VBUCK - 1) >> VSHIFT;
    const int       nblk   = (int)((n_edge + PBLK - 1) / PBLK);

    // ws layout: [histp][totals][base][pairs][partials (optional)]
    size_t histp_sz   = (size_t)NBMAX * nblk * sizeof(int);
    size_t totals_off = (histp_sz + 255) & ~(size_t)255;
    size_t base_off   = totals_off + NBMAX * sizeof(int);
    size_t pairs_off  = (base_off + (TPB + 1) * sizeof(int) + 255) & ~(size_t)255;
    size_t need1      = pairs_off + (size_t)n_edge * sizeof(unsigned long long);
    size_t part_off   = (need1 + 255) & ~(size_t)255;

    if (ws_size >= need1 && nb <= NBMAX) {
        int* histp  = (int*)d_ws;
        int* totals = (int*)((char*)d_ws + totals_off);
        int* basep  = (int*)((char*)d_ws + base_off);
        unsigned long long* pairs =
            (unsigned long long*)((char*)d_ws + pairs_off);

        hist_blocks_kernel<<<nblk, TPB, 0, stream>>>(edgeij, n_edge, nblk, histp);
        row_scan_kernel<<<nb, TPB, 0, stream>>>(histp, nblk, totals);
        base_scan_kernel<<<1, TPB, 0, stream>>>(totals, nb, basep);
        partition_kernel<<<nblk, TPB, 0, stream>>>(edgeij, edge_attr, n_edge,
                                                   nblk, histp, basep, pairs);

        // pick largest split whose partials fit in remaining ws
        int split = 0;
        for (int sp = SPLITMAX; sp >= 2; sp >>= 1) {
            if (ws_size >= part_off + (size_t)sp * n_vert * sizeof(float)) {
                split = sp; break;
            }
        }
        if (split) {
            float* partials = (float*)((char*)d_ws + part_off);
            accum_partial_kernel<<<nb * split, ATPB, 0, stream>>>(
                pairs, basep, partials, n_vert, nb, split);
            const int uthreads = (n_vert + 3) / 4;
            final_update_kernel<<<(uthreads + TPB - 1) / TPB, TPB, 0, stream>>>(
                partials, vertex_attr, g, (float*)d_out, n_vert, split);
        } else {
            accum_update_kernel<<<nb, 1024, 0, stream>>>(pairs, basep, vertex_attr,
                                                         g, (float*)d_out, n_vert);
        }
    } else {
        float* cbar = (float*)d_ws;
        hipMemsetAsync(cbar, 0, (size_t)n_vert * sizeof(float), stream);
        scatter_add_dev_kernel<<<4096, TPB, 0, stream>>>(edgeij, edge_attr, cbar,
                                                         (int)(n_edge / 4));
        update_kernel<<<(n_vert + TPB - 1) / TPB, TPB, 0, stream>>>(
            vertex_attr, cbar, g, (float*)d_out, n_vert);
    }
}

// Round 12
// 182.836 us; speedup vs baseline: 1.0175x; 1.0175x over previous
//
#include <hip/hip_runtime.h>

#define TPB    256
#define VSHIFT 12
#define VBUCK  (1 << VSHIFT)        // 4096 vertices per bucket
#define NBMAX  256                  // max buckets (1e6/4096 = 245); == TPB
#define EPT    16                   // edges/thread/round, partition
#define ROUND  (TPB * EPT)          // 4096 edges/round
#define RPB    4                    // rounds per block
#define PBLK   (ROUND * RPB)        // 16384 edges/block
#define SPLITMAX 4                  // preferred accumulate sub-blocks per bucket
#define ATPB   1024                 // accumulate threads per block
#define KDEP   8                    // ulonglong2 loads in flight per thread

__device__ __forceinline__ unsigned long long pack_pair(int d, float v) {
    return (unsigned long long)(unsigned)d |
           ((unsigned long long)__float_as_uint(v) << 32);
}

// Raw fire-and-forget LDS float atomic add (ds_add_f32).
// Low 32 bits of a generic pointer to __shared__ are the LDS byte offset.
__device__ __forceinline__ void lds_add_f32(float* addr, float v) {
    asm volatile("ds_add_f32 %0, %1"
                 :: "v"((unsigned)(uintptr_t)addr), "v"(v) : "memory");
}

// Exclusive scan across TPB threads; also returns block total (uniform).
__device__ __forceinline__ int block_excl_scan(int v, int t, int* wsum, int* total) {
    int s = v;
    #pragma unroll
    for (int d = 1; d < 64; d <<= 1) {
        int u = __shfl_up(s, d);
        if ((t & 63) >= d) s += u;
    }
    if ((t & 63) == 63) wsum[t >> 6] = s;
    __syncthreads();
    int add = 0;
    #pragma unroll
    for (int w = 0; w < TPB / 64; ++w)
        if (w < (t >> 6)) add += wsum[w];
    int tot = wsum[0] + wsum[1] + wsum[2] + wsum[3];
    __syncthreads();                 // wsum safe for reuse
    *total = tot;
    return s + add - v;
}

// Per-partition-block bucket histogram, stored transposed: histp[b][blk].
__global__ void hist_blocks_kernel(const int* __restrict__ dst, long long n_edge,
                                   int nblk, int* __restrict__ histp) {
    __shared__ int h[NBMAX];
    const int t = threadIdx.x;
    h[t] = 0;
    __syncthreads();
    const long long bbase = (long long)blockIdx.x * PBLK;
    const long long bend0 = bbase + PBLK;
    const long long bend  = bend0 < n_edge ? bend0 : n_edge;
    #pragma unroll 4
    for (int j = 0; j < PBLK / TPB / 4; ++j) {
        long long e = bbase + ((long long)j * TPB + t) * 4;
        if (e + 4 <= bend) {
            int4 d = *reinterpret_cast<const int4*>(dst + e);
            atomicAdd(&h[d.x >> VSHIFT], 1);
            atomicAdd(&h[d.y >> VSHIFT], 1);
            atomicAdd(&h[d.z >> VSHIFT], 1);
            atomicAdd(&h[d.w >> VSHIFT], 1);
        } else {
            for (int q = 0; q < 4; ++q) {
                long long ee = e + q;
                if (ee < bend) atomicAdd(&h[dst[ee] >> VSHIFT], 1);
            }
        }
    }
    __syncthreads();
    histp[(size_t)t * nblk + blockIdx.x] = h[t];
}

// One block per bucket: exclusive-scan its row of per-block counts in place;
// write the bucket total.
__global__ void row_scan_kernel(int* __restrict__ histp, int nblk,
                                int* __restrict__ totals) {
    __shared__ int wsum[TPB / 64];
    const int t = threadIdx.x;
    int* row = histp + (size_t)blockIdx.x * nblk;
    int carry = 0;
    for (int base = 0; base < nblk; base += TPB) {
        int v = (base + t < nblk) ? row[base + t] : 0;
        int tot;
        int excl = block_excl_scan(v, t, wsum, &tot);
        if (base + t < nblk) row[base + t] = carry + excl;
        carry += tot;
        __syncthreads();
    }
    if (t == 0) totals[blockIdx.x] = carry;
}

// Exclusive scan of bucket totals -> bucket base offsets (base[NBMAX+1]).
__global__ void base_scan_kernel(const int* __restrict__ totals, int nb,
                                 int* __restrict__ base) {
    __shared__ int wsum[TPB / 64];
    const int t = threadIdx.x;
    int v = (t < nb) ? totals[t] : 0;
    int tot;
    int excl = block_excl_scan(v, t, wsum, &tot);
    base[t] = excl;
    if (t == TPB - 1) base[TPB] = excl + v;
}

// Partition edges into per-bucket pair regions. Offsets fully precomputed.
// Fast path (full blocks): double-buffered register prefetch so next round's
// HBM loads are in flight during this round's LDS phases + flush.
__global__ __launch_bounds__(TPB, 4)
void partition_kernel(const int* __restrict__ dst,
                      const float* __restrict__ ea,
                      long long n_edge, int nblk,
                      const int* __restrict__ histp,
                      const int* __restrict__ base,
                      unsigned long long* __restrict__ pairs) {
    __shared__ unsigned long long stage[ROUND];   // 32 KB, bucket-sorted pairs
    __shared__ int h[NBMAX];      // round histogram
    __shared__ int pos[NBMAX];    // round scatter cursors
    __shared__ int adj[NBMAX];    // gbase - pfx per bucket
    __shared__ int wsum[TPB / 64];

    const int t = threadIdx.x;
    const long long bbase = (long long)blockIdx.x * PBLK;
    int my_gbase = base[t] + histp[(size_t)t * nblk + blockIdx.x];

    if (bbase + PBLK <= n_edge) {
        // ---------- fast path: full block, prefetch double-buffer ----------
        int4   dr[2][EPT / 4];
        float4 vr[2][EPT / 4];
        #pragma unroll
        for (int j = 0; j < EPT / 4; ++j) {
            long long e = bbase + ((long long)j * TPB + t) * 4;
            dr[0][j] = *reinterpret_cast<const int4*>(dst + e);
            vr[0][j] = *reinterpret_cast<const float4*>(ea + e);
        }
        #pragma unroll
        for (int r = 0; r < RPB; ++r) {
            const int cur = r & 1, nxt = cur ^ 1;
            if (r + 1 < RPB) {                    // issue next round's loads NOW
                const long long pb = bbase + (long long)(r + 1) * ROUND;
                #pragma unroll
                for (int j = 0; j < EPT / 4; ++j) {
                    long long e = pb + ((long long)j * TPB + t) * 4;
                    dr[nxt][j] = *reinterpret_cast<const int4*>(dst + e);
                    vr[nxt][j] = *reinterpret_cast<const float4*>(ea + e);
                }
            }
            h[t] = 0;
            __syncthreads();
            #pragma unroll
            for (int j = 0; j < EPT / 4; ++j) {
                atomicAdd(&h[dr[cur][j].x >> VSHIFT], 1);
                atomicAdd(&h[dr[cur][j].y >> VSHIFT], 1);
                atomicAdd(&h[dr[cur][j].z >> VSHIFT], 1);
                atomicAdd(&h[dr[cur][j].w >> VSHIFT], 1);
            }
            __syncthreads();
            int rt;
            int excl = block_excl_scan(h[t], t, wsum, &rt);
            pos[t] = excl;
            adj[t] = my_gbase - excl;
            __syncthreads();
            #pragma unroll
            for (int j = 0; j < EPT / 4; ++j) {
                int   dd[4] = {dr[cur][j].x, dr[cur][j].y, dr[cur][j].z, dr[cur][j].w};
                float vv[4] = {vr[cur][j].x, vr[cur][j].y, vr[cur][j].z, vr[cur][j].w};
                #pragma unroll
                for (int q = 0; q < 4; ++q) {
                    int b = dd[q] >> VSHIFT;
                    int slot = atomicAdd(&pos[b], 1);
                    stage[slot] = pack_pair(dd[q], vv[q]);
                }
            }
            __syncthreads();
            #pragma unroll
            for (int i0 = 0; i0 < ROUND; i0 += TPB) {   // rt == ROUND here
                int i = i0 + t;
                unsigned long long p = stage[i];
                int b = (int)((unsigned)(p & 0xffffffffull) >> VSHIFT);
                pairs[(size_t)(adj[b] + i)] = p;
            }
            my_gbase += h[t];
            // no trailing barrier: next round's post-reset barrier protects
            // stage (rewritten only after 3 barriers) and adj (after 2).
        }
    } else {
        // ---------- guarded tail path (last block only) ----------
        const long long bend = n_edge;
        for (int r = 0; r < RPB; ++r) {
            const long long rbase = bbase + (long long)r * ROUND;
            if (rbase >= bend) break;              // uniform across block
            h[t] = 0;
            __syncthreads();

            int4   dreg[EPT / 4];
            float4 vreg[EPT / 4];
            int    nval[EPT / 4];
            #pragma unroll
            for (int j = 0; j < EPT / 4; ++j) {
                long long e = rbase + ((long long)j * TPB + t) * 4;
                if (e + 4 <= bend) {
                    dreg[j] = *reinterpret_cast<const int4*>(dst + e);
                    vreg[j] = *reinterpret_cast<const float4*>(ea + e);
                    nval[j] = 4;
                } else {
                    int dd[4] = {0, 0, 0, 0};
                    float vv[4] = {0.f, 0.f, 0.f, 0.f};
                    int nv = 0;
                    for (int q = 0; q < 4; ++q) {
                        long long ee = e + q;
                        if (ee < bend) { dd[q] = dst[ee]; vv[q] = ea[ee]; nv = q + 1; }
                    }
                    dreg[j] = make_int4(dd[0], dd[1], dd[2], dd[3]);
                    vreg[j] = make_float4(vv[0], vv[1], vv[2], vv[3]);
                    nval[j] = nv;
                }
                if (nval[j] > 0) atomicAdd(&h[dreg[j].x >> VSHIFT], 1);
                if (nval[j] > 1) atomicAdd(&h[dreg[j].y >> VSHIFT], 1);
                if (nval[j] > 2) atomicAdd(&h[dreg[j].z >> VSHIFT], 1);
                if (nval[j] > 3) atomicAdd(&h[dreg[j].w >> VSHIFT], 1);
            }
            __syncthreads();

            int rt;
            int excl = block_excl_scan(h[t], t, wsum, &rt);
            pos[t] = excl;
            adj[t] = my_gbase - excl;
            __syncthreads();

            #pragma unroll
            for (int j = 0; j < EPT / 4; ++j) {
                int   dd[4] = {dreg[j].x, dreg[j].y, dreg[j].z, dreg[j].w};
                float vv[4] = {vreg[j].x, vreg[j].y, vreg[j].z, vreg[j].w};
                #pragma unroll
                for (int q = 0; q < 4; ++q) {
                    if (q < nval[j]) {
                        int b = dd[q] >> VSHIFT;
                        int slot = atomicAdd(&pos[b], 1);
                        stage[slot] = pack_pair(dd[q], vv[q]);
                    }
                }
            }
            __syncthreads();

            for (int i = t; i < rt; i += TPB) {
                unsigned long long p = stage[i];
                int b = (int)((unsigned)(p & 0xffffffffull) >> VSHIFT);
                pairs[(size_t)(adj[b] + i)] = p;
            }
            __syncthreads();
            my_gbase += h[t];
        }
    }
}

// split blocks per bucket: each accumulates its slice of the bucket's pairs
// into LDS via raw ds_add_f32, with the thread's whole slice (KDEP ull2)
// issued as one load batch for MLP.
__global__ __launch_bounds__(ATPB)
void accum_partial_kernel(const unsigned long long* __restrict__ pairs,
                          const int* __restrict__ base,
                          float* __restrict__ partials, int n_vert, int nb,
                          int split) {
    __shared__ __align__(16) float acc[VBUCK];
    const int b  = blockIdx.x % nb;
    const int sp = blockIdx.x / nb;
    const int t  = threadIdx.x;
    #pragma unroll
    for (int i = t; i < VBUCK; i += ATPB) acc[i] = 0.f;
    __syncthreads();

    const int s = base[b];
    const int e = base[b + 1];
    const long long len = e - s;
    const int i0 = s + (int)((len * sp) / split);
    const int i1 = s + (int)((len * (sp + 1)) / split);
    const int a0 = (i0 + 1) & ~1;          // first even index >= i0
    const int a1 = i1 & ~1;                // last even boundary <= i1

    // odd head / odd tail (at most one pair each)
    if (t == 0 && (i0 & 1) && i0 < i1) {
        unsigned long long p = pairs[i0];
        lds_add_f32(&acc[(int)(p & (VBUCK - 1))],
                    __uint_as_float((unsigned)(p >> 32)));
    }
    if (t == 1 && (i1 & 1) && (i1 - 1) >= i0) {
        unsigned long long p = pairs[i1 - 1];
        lds_add_f32(&acc[(int)(p & (VBUCK - 1))],
                    __uint_as_float((unsigned)(p >> 32)));
    }

    const int n2 = (a1 - a0) >> 1;         // ulonglong2 elements
    const ulonglong2* pv = reinterpret_cast<const ulonglong2*>(pairs + a0);

    // one deep batch: KDEP strided loads in flight, then the adds
    ulonglong2 q[KDEP];
    int cnt = 0;
    #pragma unroll
    for (int k = 0; k < KDEP; ++k) {
        int idx = t + k * ATPB;
        if (idx < n2) { q[k] = pv[idx]; cnt = k + 1; }
    }
    #pragma unroll
    for (int k = 0; k < KDEP; ++k) {
        if (k < cnt) {
            lds_add_f32(&acc[(int)(q[k].x & (VBUCK - 1))],
                        __uint_as_float((unsigned)(q[k].x >> 32)));
            lds_add_f32(&acc[(int)(q[k].y & (VBUCK - 1))],
                        __uint_as_float((unsigned)(q[k].y >> 32)));
        }
    }
    // residual (slice longer than KDEP*ATPB ull2 elements)
    for (int idx = t + KDEP * ATPB; idx < n2; idx += ATPB) {
        ulonglong2 qq = pv[idx];
        lds_add_f32(&acc[(int)(qq.x & (VBUCK - 1))],
                    __uint_as_float((unsigned)(qq.x >> 32)));
        lds_add_f32(&acc[(int)(qq.y & (VBUCK - 1))],
                    __uint_as_float((unsigned)(qq.y >> 32)));
    }
    __syncthreads();

    float* pp = partials + (size_t)sp * n_vert;
    const int vbase = b << VSHIFT;
    if (vbase + VBUCK <= n_vert) {
        reinterpret_cast<float4*>(pp + vbase)[t] =
            reinterpret_cast<const float4*>(acc)[t];
    } else {
        for (int v = t; vbase + v < n_vert; v += ATPB) pp[vbase + v] = acc[v];
    }
}

// Sum split partials + vertex update; 4 vertices/thread, float4 I/O.
__global__ void final_update_kernel(const float* __restrict__ partials,
                                    const float* __restrict__ va,
                                    const float* __restrict__ g,
                                    float* __restrict__ out, int n_vert,
                                    int split) {
    const int gt = blockIdx.x * blockDim.x + threadIdx.x;
    const float w = g[0];
    const int v0 = gt * 4;
    if (v0 + 4 <= n_vert) {
        float4 c = reinterpret_cast<const float4*>(partials)[gt];
        for (int sp = 1; sp < split; ++sp) {
            float4 c2 = reinterpret_cast<const float4*>(
                            partials + (size_t)sp * n_vert)[gt];
            c.x += c2.x; c.y += c2.y; c.z += c2.z; c.w += c2.w;
        }
        float4 f0 = reinterpret_cast<const float4*>(va)[gt * 3 + 0];
        float4 f1 = reinterpret_cast<const float4*>(va)[gt * 3 + 1];
        float4 f2 = reinterpret_cast<const float4*>(va)[gt * 3 + 2];
        float4 o0, o1, o2;
        o0.x = f0.x; o0.y = f0.y; o0.z = f0.z + w * (f0.y - c.x) / f0.x;
        o0.w = f0.w; o1.x = f1.x; o1.y = f1.y + w * (f1.x - c.y) / f0.w;
        o1.z = f1.z; o1.w = f1.w; o2.x = f2.x + w * (f1.w - c.z) / f1.z;
        o2.y = f2.y; o2.z = f2.z; o2.w = f2.w + w * (f2.z - c.w) / f2.y;
        reinterpret_cast<float4*>(out)[gt * 3 + 0] = o0;
        reinterpret_cast<float4*>(out)[gt * 3 + 1] = o1;
        reinterpret_cast<float4*>(out)[gt * 3 + 2] = o2;
    } else {
        for (int i = v0; i < n_vert; ++i) {
            float c = 0.f;
            for (int sp = 0; sp < split; ++sp)
                c += partials[(size_t)sp * n_vert + i];
            float A = va[3 * i], bb = va[3 * i + 1], x = va[3 * i + 2];
            out[3 * i]     = A;
            out[3 * i + 1] = bb;
            out[3 * i + 2] = x + w * (bb - c) / A;
        }
    }
}

// Fused path (used if partials don't fit in ws).
__global__ void accum_update_kernel(const unsigned long long* __restrict__ pairs,
                                    const int* __restrict__ base,
                                    const float* __restrict__ va,
                                    const float* __restrict__ g,
                                    float* __restrict__ out, int n_vert) {
    __shared__ __align__(16) float acc[VBUCK];
    const int b = blockIdx.x;
    const int T = blockDim.x;                  // 1024
    for (int t = threadIdx.x; t < VBUCK; t += T) acc[t] = 0.f;
    __syncthreads();
    const int s = base[b];
    const int e = base[b + 1];
    for (int i = s + threadIdx.x; i < e; i += T) {
        unsigned long long p = pairs[i];
        lds_add_f32(&acc[(int)(p & (VBUCK - 1))],
                    __uint_as_float((unsigned)(p >> 32)));
    }
    __syncthreads();

    const float w = g[0];
    const int vbase = b << VSHIFT;
    const int t = threadIdx.x;
    const int v0 = vbase + t * 4;
    if (v0 + 4 <= n_vert) {
        const int gt = v0 >> 2;
        float4 f0 = reinterpret_cast<const float4*>(va)[gt * 3 + 0];
        float4 f1 = reinterpret_cast<const float4*>(va)[gt * 3 + 1];
        float4 f2 = reinterpret_cast<const float4*>(va)[gt * 3 + 2];
        float4 c  = reinterpret_cast<const float4*>(acc)[t];
        float4 o0, o1, o2;
        o0.x = f0.x; o0.y = f0.y; o0.z = f0.z + w * (f0.y - c.x) / f0.x;
        o0.w = f0.w; o1.x = f1.x; o1.y = f1.y + w * (f1.x - c.y) / f0.w;
        o1.z = f1.z; o1.w = f1.w; o2.x = f2.x + w * (f1.w - c.z) / f1.z;
        o2.y = f2.y; o2.z = f2.z; o2.w = f2.w + w * (f2.z - c.w) / f2.y;
        reinterpret_cast<float4*>(out)[gt * 3 + 0] = o0;
        reinterpret_cast<float4*>(out)[gt * 3 + 1] = o1;
        reinterpret_cast<float4*>(out)[gt * 3 + 2] = o2;
    } else {
        for (int i = v0; i < n_vert && i < v0 + 4; ++i) {
            float A = va[3 * i], bb = va[3 * i + 1], x = va[3 * i + 2];
            out[3 * i]     = A;
            out[3 * i + 1] = bb;
            out[3 * i + 2] = x + w * (bb - acc[i - vbase]) / A;
        }
    }
}

// ---- fallback path (insufficient scratch): device-scope atomics ----
__global__ void scatter_add_dev_kernel(const int* __restrict__ dst,
                                       const float* __restrict__ ea,
                                       float* __restrict__ acc, int n_edges4) {
    int i = blockIdx.x * blockDim.x + threadIdx.x;
    const int stride = gridDim.x * blockDim.x;
    for (; i < n_edges4; i += stride) {
        int4   d = reinterpret_cast<const int4*>(dst)[i];
        float4 v = reinterpret_cast<const float4*>(ea)[i];
        atomicAdd(&acc[d.x], v.x);
        atomicAdd(&acc[d.y], v.y);
        atomicAdd(&acc[d.z], v.z);
        atomicAdd(&acc[d.w], v.w);
    }
}

__global__ void update_kernel(const float* __restrict__ va,
                              const float* __restrict__ cbar,
                              const float* __restrict__ g,
                              float* __restrict__ out, int n) {
    int i = blockIdx.x * blockDim.x + threadIdx.x;
    if (i >= n) return;
    float A = va[3 * i], b = va[3 * i + 1], x = va[3 * i + 2];
    out[3 * i]     = A;
    out[3 * i + 1] = b;
    out[3 * i + 2] = x + g[0] * (b - cbar[i]) / A;
}

extern "C" void kernel_launch(void* const* d_in, const int* in_sizes, int n_in,
                              void* d_out, int out_size, void* d_ws, size_t ws_size,
                              hipStream_t stream) {
    const float* vertex_attr = (const float*)d_in[0];
    const int*   edgeij      = (const int*)d_in[1];   // row 0 = dst
    const float* edge_attr   = (const float*)d_in[2];
    const float* g           = (const float*)d_in[3];

    const int       n_vert = in_sizes[0] / 3;
    const long long n_edge = in_sizes[2];
    const int       nb     = (n_vert + VBUCK - 1) >> VSHIFT;
    const int       nblk   = (int)((n_edge + PBLK - 1) / PBLK);

    // ws layout: [histp][totals][base][pairs][partials (optional)]
    size_t histp_sz   = (size_t)NBMAX * nblk * sizeof(int);
    size_t totals_off = (histp_sz + 255) & ~(size_t)255;
    size_t base_off   = totals_off + NBMAX * sizeof(int);
    size_t pairs_off  = (base_off + (TPB + 1) * sizeof(int) + 255) & ~(size_t)255;
    size_t need1      = pairs_off + (size_t)n_edge * sizeof(unsigned long long);
    size_t part_off   = (need1 + 255) & ~(size_t)255;

    if (ws_size >= need1 && nb <= NBMAX) {
        int* histp  = (int*)d_ws;
        int* totals = (int*)((char*)d_ws + totals_off);
        int* basep  = (int*)((char*)d_ws + base_off);
        unsigned long long* pairs =
            (unsigned long long*)((char*)d_ws + pairs_off);

        hist_blocks_kernel<<<nblk, TPB, 0, stream>>>(edgeij, n_edge, nblk, histp);
        row_scan_kernel<<<nb, TPB, 0, stream>>>(histp, nblk, totals);
        base_scan_kernel<<<1, TPB, 0, stream>>>(totals, nb, basep);
        partition_kernel<<<nblk, TPB, 0, stream>>>(edgeij, edge_attr, n_edge,
                                                   nblk, histp, basep, pairs);

        // pick largest split whose partials fit in remaining ws
        int split = 0;
        for (int sp = SPLITMAX; sp >= 2; sp >>= 1) {
            if (ws_size >= part_off + (size_t)sp * n_vert * sizeof(float)) {
                split = sp; break;
            }
        }
        if (split) {
            float* partials = (float*)((char*)d_ws + part_off);
            accum_partial_kernel<<<nb * split, ATPB, 0, stream>>>(
                pairs, basep, partials, n_vert, nb, split);
            const int uthreads = (n_vert + 3) / 4;
            final_update_kernel<<<(uthreads + TPB - 1) / TPB, TPB, 0, stream>>>(
                partials, vertex_attr, g, (float*)d_out, n_vert, split);
        } else {
            accum_update_kernel<<<nb, 1024, 0, stream>>>(pairs, basep, vertex_attr,
                                                         g, (float*)d_out, n_vert);
        }
    } else {
        float* cbar = (float*)d_ws;
        hipMemsetAsync(cbar, 0, (size_t)n_vert * sizeof(float), stream);
        scatter_add_dev_kernel<<<4096, TPB, 0, stream>>>(edgeij, edge_attr, cbar,
                                                         (int)(n_edge / 4));
        update_kernel<<<(n_vert + TPB - 1) / TPB, TPB, 0, stream>>>(
            vertex_attr, cbar, g, (float*)d_out, n_vert);
    }
}

// Round 13
// 182.270 us; speedup vs baseline: 1.0207x; 1.0031x over previous
//
#include <hip/hip_runtime.h>

#define TPB    256
#define VSHIFT 12
#define VBUCK  (1 << VSHIFT)        // 4096 vertices per bucket
#define NBMAX  256                  // max buckets (1e6/4096 = 245); == TPB
#define EPT    16                   // edges/thread/round, partition
#define ROUND  (TPB * EPT)          // 4096 edges/round
#define RPB    4                    // rounds per block
#define PBLK   (ROUND * RPB)        // 16384 edges/block
#define SPLITMAX 4                  // preferred accumulate sub-blocks per bucket
#define ATPB   1024                 // accumulate threads per block
#define KDEP   8                    // ulonglong2 loads in flight per thread

__device__ __forceinline__ unsigned long long pack_pair(int d, float v) {
    return (unsigned long long)(unsigned)d |
           ((unsigned long long)__float_as_uint(v) << 32);
}

// Raw fire-and-forget LDS float atomic add (ds_add_f32).
__device__ __forceinline__ void lds_add_f32(float* addr, float v) {
    asm volatile("ds_add_f32 %0, %1"
                 :: "v"((unsigned)(uintptr_t)addr), "v"(v) : "memory");
}

// Exclusive scan across TPB threads; also returns block total (uniform).
__device__ __forceinline__ int block_excl_scan(int v, int t, int* wsum, int* total) {
    int s = v;
    #pragma unroll
    for (int d = 1; d < 64; d <<= 1) {
        int u = __shfl_up(s, d);
        if ((t & 63) >= d) s += u;
    }
    if ((t & 63) == 63) wsum[t >> 6] = s;
    __syncthreads();
    int add = 0;
    #pragma unroll
    for (int w = 0; w < TPB / 64; ++w)
        if (w < (t >> 6)) add += wsum[w];
    int tot = wsum[0] + wsum[1] + wsum[2] + wsum[3];
    __syncthreads();                 // wsum safe for reuse
    *total = tot;
    return s + add - v;
}

// Per-partition-block bucket histogram, stored transposed: histp[b][blk].
__global__ void hist_blocks_kernel(const int* __restrict__ dst, long long n_edge,
                                   int nblk, int* __restrict__ histp) {
    __shared__ int h[NBMAX];
    const int t = threadIdx.x;
    h[t] = 0;
    __syncthreads();
    const long long bbase = (long long)blockIdx.x * PBLK;
    const long long bend0 = bbase + PBLK;
    const long long bend  = bend0 < n_edge ? bend0 : n_edge;
    #pragma unroll 4
    for (int j = 0; j < PBLK / TPB / 4; ++j) {
        long long e = bbase + ((long long)j * TPB + t) * 4;
        if (e + 4 <= bend) {
            int4 d = *reinterpret_cast<const int4*>(dst + e);
            atomicAdd(&h[d.x >> VSHIFT], 1);
            atomicAdd(&h[d.y >> VSHIFT], 1);
            atomicAdd(&h[d.z >> VSHIFT], 1);
            atomicAdd(&h[d.w >> VSHIFT], 1);
        } else {
            for (int q = 0; q < 4; ++q) {
                long long ee = e + q;
                if (ee < bend) atomicAdd(&h[dst[ee] >> VSHIFT], 1);
            }
        }
    }
    __syncthreads();
    histp[(size_t)t * nblk + blockIdx.x] = h[t];
}

// One block per bucket: exclusive-scan its row of per-block counts in place;
// write the bucket total.
__global__ void row_scan_kernel(int* __restrict__ histp, int nblk,
                                int* __restrict__ totals) {
    __shared__ int wsum[TPB / 64];
    const int t = threadIdx.x;
    int* row = histp + (size_t)blockIdx.x * nblk;
    int carry = 0;
    for (int base = 0; base < nblk; base += TPB) {
        int v = (base + t < nblk) ? row[base + t] : 0;
        int tot;
        int excl = block_excl_scan(v, t, wsum, &tot);
        if (base + t < nblk) row[base + t] = carry + excl;
        carry += tot;
        __syncthreads();
    }
    if (t == 0) totals[blockIdx.x] = carry;
}

// Exclusive scan of bucket totals -> bucket base offsets (base[NBMAX+1]).
__global__ void base_scan_kernel(const int* __restrict__ totals, int nb,
                                 int* __restrict__ base) {
    __shared__ int wsum[TPB / 64];
    const int t = threadIdx.x;
    int v = (t < nb) ? totals[t] : 0;
    int tot;
    int excl = block_excl_scan(v, t, wsum, &tot);
    base[t] = excl;
    if (t == TPB - 1) base[TPB] = excl + v;
}

// Partition edges into per-bucket pair regions. Offsets fully precomputed.
// Fast path (full blocks): double-buffered register prefetch so next round's
// HBM loads are in flight during this round's LDS phases + flush.
__global__ __launch_bounds__(TPB, 4)
void partition_kernel(const int* __restrict__ dst,
                      const float* __restrict__ ea,
                      long long n_edge, int nblk,
                      const int* __restrict__ histp,
                      const int* __restrict__ base,
                      unsigned long long* __restrict__ pairs) {
    __shared__ unsigned long long stage[ROUND];   // 32 KB, bucket-sorted pairs
    __shared__ int h[NBMAX];      // round histogram
    __shared__ int pos[NBMAX];    // round scatter cursors
    __shared__ int adj[NBMAX];    // gbase - pfx per bucket
    __shared__ int wsum[TPB / 64];

    const int t = threadIdx.x;
    const long long bbase = (long long)blockIdx.x * PBLK;
    int my_gbase = base[t] + histp[(size_t)t * nblk + blockIdx.x];

    if (bbase + PBLK <= n_edge) {
        // ---------- fast path: full block, prefetch double-buffer ----------
        int4   dr[2][EPT / 4];
        float4 vr[2][EPT / 4];
        #pragma unroll
        for (int j = 0; j < EPT / 4; ++j) {
            long long e = bbase + ((long long)j * TPB + t) * 4;
            dr[0][j] = *reinterpret_cast<const int4*>(dst + e);
            vr[0][j] = *reinterpret_cast<const float4*>(ea + e);
        }
        #pragma unroll
        for (int r = 0; r < RPB; ++r) {
            const int cur = r & 1, nxt = cur ^ 1;
            if (r + 1 < RPB) {                    // issue next round's loads NOW
                const long long pb = bbase + (long long)(r + 1) * ROUND;
                #pragma unroll
                for (int j = 0; j < EPT / 4; ++j) {
                    long long e = pb + ((long long)j * TPB + t) * 4;
                    dr[nxt][j] = *reinterpret_cast<const int4*>(dst + e);
                    vr[nxt][j] = *reinterpret_cast<const float4*>(ea + e);
                }
            }
            h[t] = 0;
            __syncthreads();
            #pragma unroll
            for (int j = 0; j < EPT / 4; ++j) {
                atomicAdd(&h[dr[cur][j].x >> VSHIFT], 1);
                atomicAdd(&h[dr[cur][j].y >> VSHIFT], 1);
                atomicAdd(&h[dr[cur][j].z >> VSHIFT], 1);
                atomicAdd(&h[dr[cur][j].w >> VSHIFT], 1);
            }
            __syncthreads();
            int rt;
            int excl = block_excl_scan(h[t], t, wsum, &rt);
            pos[t] = excl;
            adj[t] = my_gbase - excl;
            __syncthreads();
            #pragma unroll
            for (int j = 0; j < EPT / 4; ++j) {
                int   dd[4] = {dr[cur][j].x, dr[cur][j].y, dr[cur][j].z, dr[cur][j].w};
                float vv[4] = {vr[cur][j].x, vr[cur][j].y, vr[cur][j].z, vr[cur][j].w};
                #pragma unroll
                for (int q = 0; q < 4; ++q) {
                    int b = dd[q] >> VSHIFT;
                    int slot = atomicAdd(&pos[b], 1);
                    stage[slot] = pack_pair(dd[q], vv[q]);
                }
            }
            __syncthreads();
            #pragma unroll
            for (int i0 = 0; i0 < ROUND; i0 += TPB) {   // rt == ROUND here
                int i = i0 + t;
                unsigned long long p = stage[i];
                int b = (int)((unsigned)(p & 0xffffffffull) >> VSHIFT);
                pairs[(size_t)(adj[b] + i)] = p;
            }
            my_gbase += h[t];
        }
    } else {
        // ---------- guarded tail path (last block only) ----------
        const long long bend = n_edge;
        for (int r = 0; r < RPB; ++r) {
            const long long rbase = bbase + (long long)r * ROUND;
            if (rbase >= bend) break;              // uniform across block
            h[t] = 0;
            __syncthreads();

            int4   dreg[EPT / 4];
            float4 vreg[EPT / 4];
            int    nval[EPT / 4];
            #pragma unroll
            for (int j = 0; j < EPT / 4; ++j) {
                long long e = rbase + ((long long)j * TPB + t) * 4;
                if (e + 4 <= bend) {
                    dreg[j] = *reinterpret_cast<const int4*>(dst + e);
                    vreg[j] = *reinterpret_cast<const float4*>(ea + e);
                    nval[j] = 4;
                } else {
                    int dd[4] = {0, 0, 0, 0};
                    float vv[4] = {0.f, 0.f, 0.f, 0.f};
                    int nv = 0;
                    for (int q = 0; q < 4; ++q) {
                        long long ee = e + q;
                        if (ee < bend) { dd[q] = dst[ee]; vv[q] = ea[ee]; nv = q + 1; }
                    }
                    dreg[j] = make_int4(dd[0], dd[1], dd[2], dd[3]);
                    vreg[j] = make_float4(vv[0], vv[1], vv[2], vv[3]);
                    nval[j] = nv;
                }
                if (nval[j] > 0) atomicAdd(&h[dreg[j].x >> VSHIFT], 1);
                if (nval[j] > 1) atomicAdd(&h[dreg[j].y >> VSHIFT], 1);
                if (nval[j] > 2) atomicAdd(&h[dreg[j].z >> VSHIFT], 1);
                if (nval[j] > 3) atomicAdd(&h[dreg[j].w >> VSHIFT], 1);
            }
            __syncthreads();

            int rt;
            int excl = block_excl_scan(h[t], t, wsum, &rt);
            pos[t] = excl;
            adj[t] = my_gbase - excl;
            __syncthreads();

            #pragma unroll
            for (int j = 0; j < EPT / 4; ++j) {
                int   dd[4] = {dreg[j].x, dreg[j].y, dreg[j].z, dreg[j].w};
                float vv[4] = {vreg[j].x, vreg[j].y, vreg[j].z, vreg[j].w};
                #pragma unroll
                for (int q = 0; q < 4; ++q) {
                    if (q < nval[j]) {
                        int b = dd[q] >> VSHIFT;
                        int slot = atomicAdd(&pos[b], 1);
                        stage[slot] = pack_pair(dd[q], vv[q]);
                    }
                }
            }
            __syncthreads();

            for (int i = t; i < rt; i += TPB) {
                unsigned long long p = stage[i];
                int b = (int)((unsigned)(p & 0xffffffffull) >> VSHIFT);
                pairs[(size_t)(adj[b] + i)] = p;
            }
            __syncthreads();
            my_gbase += h[t];
        }
    }
}

// split blocks per bucket: each accumulates its slice of the bucket's pairs
// into LDS. All KDEP loads are UNGUARDED (index clamped to n2-1) so the
// compiler must keep them batched in flight; only the adds are guarded.
__global__ __launch_bounds__(ATPB)
void accum_partial_kernel(const unsigned long long* __restrict__ pairs,
                          const int* __restrict__ base,
                          float* __restrict__ partials, int n_vert, int nb,
                          int split) {
    __shared__ __align__(16) float acc[VBUCK];
    const int b  = blockIdx.x % nb;
    const int sp = blockIdx.x / nb;
    const int t  = threadIdx.x;
    #pragma unroll
    for (int i = t; i < VBUCK; i += ATPB) acc[i] = 0.f;
    __syncthreads();

    const int s = base[b];
    const int e = base[b + 1];
    const long long len = e - s;
    const int i0 = s + (int)((len * sp) / split);
    const int i1 = s + (int)((len * (sp + 1)) / split);
    const int a0 = (i0 + 1) & ~1;          // first even index >= i0
    const int a1 = i1 & ~1;                // last even boundary <= i1

    // odd head / odd tail (at most one pair each)
    if (t == 0 && (i0 & 1) && i0 < i1) {
        unsigned long long p = pairs[i0];
        lds_add_f32(&acc[(int)(p & (VBUCK - 1))],
                    __uint_as_float((unsigned)(p >> 32)));
    }
    if (t == 1 && (i1 & 1) && (i1 - 1) >= i0) {
        unsigned long long p = pairs[i1 - 1];
        lds_add_f32(&acc[(int)(p & (VBUCK - 1))],
                    __uint_as_float((unsigned)(p >> 32)));
    }

    const int n2 = (a1 - a0) >> 1;         // ulonglong2 elements
    if (n2 > 0) {
        const ulonglong2* pv = reinterpret_cast<const ulonglong2*>(pairs + a0);
        const int nm1 = n2 - 1;
        for (int bb = 0; bb < n2; bb += KDEP * ATPB) {
            ulonglong2 q[KDEP];
            int idx[KDEP];
            #pragma unroll
            for (int k = 0; k < KDEP; ++k) {
                idx[k] = bb + t + k * ATPB;
                int ci = idx[k] < nm1 ? idx[k] : nm1;   // clamp: load ALWAYS
                q[k] = pv[ci];
            }
            #pragma unroll
            for (int k = 0; k < KDEP; ++k) {
                if (idx[k] < n2) {
                    lds_add_f32(&acc[(int)(q[k].x & (VBUCK - 1))],
                                __uint_as_float((unsigned)(q[k].x >> 32)));
                    lds_add_f32(&acc[(int)(q[k].y & (VBUCK - 1))],
                                __uint_as_float((unsigned)(q[k].y >> 32)));
                }
            }
        }
    }
    __syncthreads();

    float* pp = partials + (size_t)sp * n_vert;
    const int vbase = b << VSHIFT;
    if (vbase + VBUCK <= n_vert) {
        reinterpret_cast<float4*>(pp + vbase)[t] =
            reinterpret_cast<const float4*>(acc)[t];
    } else {
        for (int v = t; vbase + v < n_vert; v += ATPB) pp[vbase + v] = acc[v];
    }
}

// Sum split partials + vertex update; 4 vertices/thread, float4 I/O.
__global__ void final_update_kernel(const float* __restrict__ partials,
                                    const float* __restrict__ va,
                                    const float* __restrict__ g,
                                    float* __restrict__ out, int n_vert,
                                    int split) {
    const int gt = blockIdx.x * blockDim.x + threadIdx.x;
    const float w = g[0];
    const int v0 = gt * 4;
    if (v0 + 4 <= n_vert) {
        float4 c = reinterpret_cast<const float4*>(partials)[gt];
        for (int sp = 1; sp < split; ++sp) {
            float4 c2 = reinterpret_cast<const float4*>(
                            partials + (size_t)sp * n_vert)[gt];
            c.x += c2.x; c.y += c2.y; c.z += c2.z; c.w += c2.w;
        }
        float4 f0 = reinterpret_cast<const float4*>(va)[gt * 3 + 0];
        float4 f1 = reinterpret_cast<const float4*>(va)[gt * 3 + 1];
        float4 f2 = reinterpret_cast<const float4*>(va)[gt * 3 + 2];
        float4 o0, o1, o2;
        o0.x = f0.x; o0.y = f0.y; o0.z = f0.z + w * (f0.y - c.x) / f0.x;
        o0.w = f0.w; o1.x = f1.x; o1.y = f1.y + w * (f1.x - c.y) / f0.w;
        o1.z = f1.z; o1.w = f1.w; o2.x = f2.x + w * (f1.w - c.z) / f1.z;
        o2.y = f2.y; o2.z = f2.z; o2.w = f2.w + w * (f2.z - c.w) / f2.y;
        reinterpret_cast<float4*>(out)[gt * 3 + 0] = o0;
        reinterpret_cast<float4*>(out)[gt * 3 + 1] = o1;
        reinterpret_cast<float4*>(out)[gt * 3 + 2] = o2;
    } else {
        for (int i = v0; i < n_vert; ++i) {
            float c = 0.f;
            for (int sp = 0; sp < split; ++sp)
                c += partials[(size_t)sp * n_vert + i];
            float A = va[3 * i], bb = va[3 * i + 1], x = va[3 * i + 2];
            out[3 * i]     = A;
            out[3 * i + 1] = bb;
            out[3 * i + 2] = x + w * (bb - c) / A;
        }
    }
}

// Fused path (used if partials don't fit in ws).
__global__ void accum_update_kernel(const unsigned long long* __restrict__ pairs,
                                    const int* __restrict__ base,
                                    const float* __restrict__ va,
                                    const float* __restrict__ g,
                                    float* __restrict__ out, int n_vert) {
    __shared__ __align__(16) float acc[VBUCK];
    const int b = blockIdx.x;
    const int T = blockDim.x;                  // 1024
    for (int t = threadIdx.x; t < VBUCK; t += T) acc[t] = 0.f;
    __syncthreads();
    const int s = base[b];
    const int e = base[b + 1];
    for (int i = s + threadIdx.x; i < e; i += T) {
        unsigned long long p = pairs[i];
        lds_add_f32(&acc[(int)(p & (VBUCK - 1))],
                    __uint_as_float((unsigned)(p >> 32)));
    }
    __syncthreads();

    const float w = g[0];
    const int vbase = b << VSHIFT;
    const int t = threadIdx.x;
    const int v0 = vbase + t * 4;
    if (v0 + 4 <= n_vert) {
        const int gt = v0 >> 2;
        float4 f0 = reinterpret_cast<const float4*>(va)[gt * 3 + 0];
        float4 f1 = reinterpret_cast<const float4*>(va)[gt * 3 + 1];
        float4 f2 = reinterpret_cast<const float4*>(va)[gt * 3 + 2];
        float4 c  = reinterpret_cast<const float4*>(acc)[t];
        float4 o0, o1, o2;
        o0.x = f0.x; o0.y = f0.y; o0.z = f0.z + w * (f0.y - c.x) / f0.x;
        o0.w = f0.w; o1.x = f1.x; o1.y = f1.y + w * (f1.x - c.y) / f0.w;
        o1.z = f1.z; o1.w = f1.w; o2.x = f2.x + w * (f1.w - c.z) / f1.z;
        o2.y = f2.y; o2.z = f2.z; o2.w = f2.w + w * (f2.z - c.w) / f2.y;
        reinterpret_cast<float4*>(out)[gt * 3 + 0] = o0;
        reinterpret_cast<float4*>(out)[gt * 3 + 1] = o1;
        reinterpret_cast<float4*>(out)[gt * 3 + 2] = o2;
    } else {
        for (int i = v0; i < n_vert && i < v0 + 4; ++i) {
            float A = va[3 * i], bb = va[3 * i + 1], x = va[3 * i + 2];
            out[3 * i]     = A;
            out[3 * i + 1] = bb;
            out[3 * i + 2] = x + w * (bb - acc[i - vbase]) / A;
        }
    }
}

// ---- fallback path (insufficient scratch): device-scope atomics ----
__global__ void scatter_add_dev_kernel(const int* __restrict__ dst,
                                       const float* __restrict__ ea,
                                       float* __restrict__ acc, int n_edges4) {
    int i = blockIdx.x * blockDim.x + threadIdx.x;
    const int stride = gridDim.x * blockDim.x;
    for (; i < n_edges4; i += stride) {
        int4   d = reinterpret_cast<const int4*>(dst)[i];
        float4 v = reinterpret_cast<const float4*>(ea)[i];
        atomicAdd(&acc[d.x], v.x);
        atomicAdd(&acc[d.y], v.y);
        atomicAdd(&acc[d.z], v.z);
        atomicAdd(&acc[d.w], v.w);
    }
}

__global__ void update_kernel(const float* __restrict__ va,
                              const float* __restrict__ cbar,
                              const float* __restrict__ g,
                              float* __restrict__ out, int n) {
    int i = blockIdx.x * blockDim.x + threadIdx.x;
    if (i >= n) return;
    float A = va[3 * i], b = va[3 * i + 1], x = va[3 * i + 2];
    out[3 * i]     = A;
    out[3 * i + 1] = b;
    out[3 * i + 2] = x + g[0] * (b - cbar[i]) / A;
}

extern "C" void kernel_launch(void* const* d_in, const int* in_sizes, int n_in,
                              void* d_out, int out_size, void* d_ws, size_t ws_size,
                              hipStream_t stream) {
    const float* vertex_attr = (const float*)d_in[0];
    const int*   edgeij      = (const int*)d_in[1];   // row 0 = dst
    const float* edge_attr   = (const float*)d_in[2];
    const float* g           = (const float*)d_in[3];

    const int       n_vert = in_sizes[0] / 3;
    const long long n_edge = in_sizes[2];
    const int       nb     = (n_vert + VBUCK - 1) >> VSHIFT;
    const int       nblk   = (int)((n_edge + PBLK - 1) / PBLK);

    // ws layout: [histp][totals][base][pairs][partials (optional)]
    size_t histp_sz   = (size_t)NBMAX * nblk * sizeof(int);
    size_t totals_off = (histp_sz + 255) & ~(size_t)255;
    size_t base_off   = totals_off + NBMAX * sizeof(int);
    size_t pairs_off  = (base_off + (TPB + 1) * sizeof(int) + 255) & ~(size_t)255;
    size_t need1      = pairs_off + (size_t)n_edge * sizeof(unsigned long long);
    size_t part_off   = (need1 + 255) & ~(size_t)255;

    if (ws_size >= need1 && nb <= NBMAX) {
        int* histp  = (int*)d_ws;
        int* totals = (int*)((char*)d_ws + totals_off);
        int* basep  = (int*)((char*)d_ws + base_off);
        unsigned long long* pairs =
            (unsigned long long*)((char*)d_ws + pairs_off);

        hist_blocks_kernel<<<nblk, TPB, 0, stream>>>(edgeij, n_edge, nblk, histp);
        row_scan_kernel<<<nb, TPB, 0, stream>>>(histp, nblk, totals);
        base_scan_kernel<<<1, TPB, 0, stream>>>(totals, nb, basep);
        partition_kernel<<<nblk, TPB, 0, stream>>>(edgeij, edge_attr, n_edge,
                                                   nblk, histp, basep, pairs);

        // pick largest split whose partials fit in remaining ws
        int split = 0;
        for (int sp = SPLITMAX; sp >= 2; sp >>= 1) {
            if (ws_size >= part_off + (size_t)sp * n_vert * sizeof(float)) {
                split = sp; break;
            }
        }
        if (split) {
            float* partials = (float*)((char*)d_ws + part_off);
            accum_partial_kernel<<<nb * split, ATPB, 0, stream>>>(
                pairs, basep, partials, n_vert, nb, split);
            const int uthreads = (n_vert + 3) / 4;
            final_update_kernel<<<(uthreads + TPB - 1) / TPB, TPB, 0, stream>>>(
                partials, vertex_attr, g, (float*)d_out, n_vert, split);
        } else {
            accum_update_kernel<<<nb, 1024, 0, stream>>>(pairs, basep, vertex_attr,
                                                         g, (float*)d_out, n_vert);
        }
    } else {
        float* cbar = (float*)d_ws;
        hipMemsetAsync(cbar, 0, (size_t)n_vert * sizeof(float), stream);
        scatter_add_dev_kernel<<<4096, TPB, 0, stream>>>(edgeij, edge_attr, cbar,
                                                         (int)(n_edge / 4));
        update_kernel<<<(n_vert + TPB - 1) / TPB, TPB, 0, stream>>>(
            vertex_attr, cbar, g, (float*)d_out, n_vert);
    }
}

// Round 14
// 182.256 us; speedup vs baseline: 1.0208x; 1.0001x over previous
//
#include <hip/hip_runtime.h>

#define TPB    256
#define VSHIFT 12
#define VBUCK  (1 << VSHIFT)        // 4096 vertices per bucket
#define NBMAX  256                  // max buckets (1e6/4096 = 245); == TPB
#define EPT    16                   // edges/thread/round, partition
#define ROUND  (TPB * EPT)          // 4096 edges/round
#define RPB    4                    // rounds per block
#define PBLK   (ROUND * RPB)        // 16384 edges/block
#define SPLITMAX 4                  // preferred accumulate sub-blocks per bucket
#define ATPB   1024                 // accumulate threads per block
#define KDEP   8                    // 16B loads in flight per thread

typedef unsigned uint32x4 __attribute__((ext_vector_type(4)));

__device__ __forceinline__ unsigned long long pack_pair(int d, float v) {
    return (unsigned long long)(unsigned)d |
           ((unsigned long long)__float_as_uint(v) << 32);
}

// Raw fire-and-forget LDS float atomic add (ds_add_f32).
__device__ __forceinline__ void lds_add_f32(float* addr, float v) {
    asm volatile("ds_add_f32 %0, %1"
                 :: "v"((unsigned)(uintptr_t)addr), "v"(v) : "memory");
}

// Raw 16B global load, NOT waited — caller must s_waitcnt vmcnt(0) before use.
__device__ __forceinline__ uint32x4 gload16_async(const void* p) {
    uint32x4 r;
    asm volatile("global_load_dwordx4 %0, %1, off"
                 : "=&v"(r) : "v"(p));
    return r;
}

// Exclusive scan across TPB threads; also returns block total (uniform).
__device__ __forceinline__ int block_excl_scan(int v, int t, int* wsum, int* total) {
    int s = v;
    #pragma unroll
    for (int d = 1; d < 64; d <<= 1) {
        int u = __shfl_up(s, d);
        if ((t & 63) >= d) s += u;
    }
    if ((t & 63) == 63) wsum[t >> 6] = s;
    __syncthreads();
    int add = 0;
    #pragma unroll
    for (int w = 0; w < TPB / 64; ++w)
        if (w < (t >> 6)) add += wsum[w];
    int tot = wsum[0] + wsum[1] + wsum[2] + wsum[3];
    __syncthreads();                 // wsum safe for reuse
    *total = tot;
    return s + add - v;
}

// Per-partition-block bucket histogram, stored transposed: histp[b][blk].
__global__ void hist_blocks_kernel(const int* __restrict__ dst, long long n_edge,
                                   int nblk, int* __restrict__ histp) {
    __shared__ int h[NBMAX];
    const int t = threadIdx.x;
    h[t] = 0;
    __syncthreads();
    const long long bbase = (long long)blockIdx.x * PBLK;
    const long long bend0 = bbase + PBLK;
    const long long bend  = bend0 < n_edge ? bend0 : n_edge;
    #pragma unroll 4
    for (int j = 0; j < PBLK / TPB / 4; ++j) {
        long long e = bbase + ((long long)j * TPB + t) * 4;
        if (e + 4 <= bend) {
            int4 d = *reinterpret_cast<const int4*>(dst + e);
            atomicAdd(&h[d.x >> VSHIFT], 1);
            atomicAdd(&h[d.y >> VSHIFT], 1);
            atomicAdd(&h[d.z >> VSHIFT], 1);
            atomicAdd(&h[d.w >> VSHIFT], 1);
        } else {
            for (int q = 0; q < 4; ++q) {
                long long ee = e + q;
                if (ee < bend) atomicAdd(&h[dst[ee] >> VSHIFT], 1);
            }
        }
    }
    __syncthreads();
    histp[(size_t)t * nblk + blockIdx.x] = h[t];
}

// One block per bucket: exclusive-scan its row of per-block counts in place;
// write the bucket total.
__global__ void row_scan_kernel(int* __restrict__ histp, int nblk,
                                int* __restrict__ totals) {
    __shared__ int wsum[TPB / 64];
    const int t = threadIdx.x;
    int* row = histp + (size_t)blockIdx.x * nblk;
    int carry = 0;
    for (int base = 0; base < nblk; base += TPB) {
        int v = (base + t < nblk) ? row[base + t] : 0;
        int tot;
        int excl = block_excl_scan(v, t, wsum, &tot);
        if (base + t < nblk) row[base + t] = carry + excl;
        carry += tot;
        __syncthreads();
    }
    if (t == 0) totals[blockIdx.x] = carry;
}

// Exclusive scan of bucket totals -> bucket base offsets (base[NBMAX+1]).
__global__ void base_scan_kernel(const int* __restrict__ totals, int nb,
                                 int* __restrict__ base) {
    __shared__ int wsum[TPB / 64];
    const int t = threadIdx.x;
    int v = (t < nb) ? totals[t] : 0;
    int tot;
    int excl = block_excl_scan(v, t, wsum, &tot);
    base[t] = excl;
    if (t == TPB - 1) base[TPB] = excl + v;
}

// Partition edges into per-bucket pair regions. Offsets fully precomputed.
// Fast path (full blocks): double-buffered register prefetch so next round's
// HBM loads are in flight during this round's LDS phases + flush.
__global__ __launch_bounds__(TPB, 4)
void partition_kernel(const int* __restrict__ dst,
                      const float* __restrict__ ea,
                      long long n_edge, int nblk,
                      const int* __restrict__ histp,
                      const int* __restrict__ base,
                      unsigned long long* __restrict__ pairs) {
    __shared__ unsigned long long stage[ROUND];   // 32 KB, bucket-sorted pairs
    __shared__ int h[NBMAX];      // round histogram
    __shared__ int pos[NBMAX];    // round scatter cursors
    __shared__ int adj[NBMAX];    // gbase - pfx per bucket
    __shared__ int wsum[TPB / 64];

    const int t = threadIdx.x;
    const long long bbase = (long long)blockIdx.x * PBLK;
    int my_gbase = base[t] + histp[(size_t)t * nblk + blockIdx.x];

    if (bbase + PBLK <= n_edge) {
        // ---------- fast path: full block, prefetch double-buffer ----------
        int4   dr[2][EPT / 4];
        float4 vr[2][EPT / 4];
        #pragma unroll
        for (int j = 0; j < EPT / 4; ++j) {
            long long e = bbase + ((long long)j * TPB + t) * 4;
            dr[0][j] = *reinterpret_cast<const int4*>(dst + e);
            vr[0][j] = *reinterpret_cast<const float4*>(ea + e);
        }
        #pragma unroll
        for (int r = 0; r < RPB; ++r) {
            const int cur = r & 1, nxt = cur ^ 1;
            if (r + 1 < RPB) {                    // issue next round's loads NOW
                const long long pb = bbase + (long long)(r + 1) * ROUND;
                #pragma unroll
                for (int j = 0; j < EPT / 4; ++j) {
                    long long e = pb + ((long long)j * TPB + t) * 4;
                    dr[nxt][j] = *reinterpret_cast<const int4*>(dst + e);
                    vr[nxt][j] = *reinterpret_cast<const float4*>(ea + e);
                }
            }
            h[t] = 0;
            __syncthreads();
            #pragma unroll
            for (int j = 0; j < EPT / 4; ++j) {
                atomicAdd(&h[dr[cur][j].x >> VSHIFT], 1);
                atomicAdd(&h[dr[cur][j].y >> VSHIFT], 1);
                atomicAdd(&h[dr[cur][j].z >> VSHIFT], 1);
                atomicAdd(&h[dr[cur][j].w >> VSHIFT], 1);
            }
            __syncthreads();
            int rt;
            int excl = block_excl_scan(h[t], t, wsum, &rt);
            pos[t] = excl;
            adj[t] = my_gbase - excl;
            __syncthreads();
            #pragma unroll
            for (int j = 0; j < EPT / 4; ++j) {
                int   dd[4] = {dr[cur][j].x, dr[cur][j].y, dr[cur][j].z, dr[cur][j].w};
                float vv[4] = {vr[cur][j].x, vr[cur][j].y, vr[cur][j].z, vr[cur][j].w};
                #pragma unroll
                for (int q = 0; q < 4; ++q) {
                    int b = dd[q] >> VSHIFT;
                    int slot = atomicAdd(&pos[b], 1);
                    stage[slot] = pack_pair(dd[q], vv[q]);
                }
            }
            __syncthreads();
            #pragma unroll
            for (int i0 = 0; i0 < ROUND; i0 += TPB) {   // rt == ROUND here
                int i = i0 + t;
                unsigned long long p = stage[i];
                int b = (int)((unsigned)(p & 0xffffffffull) >> VSHIFT);
                pairs[(size_t)(adj[b] + i)] = p;
            }
            my_gbase += h[t];
        }
    } else {
        // ---------- guarded tail path (last block only) ----------
        const long long bend = n_edge;
        for (int r = 0; r < RPB; ++r) {
            const long long rbase = bbase + (long long)r * ROUND;
            if (rbase >= bend) break;              // uniform across block
            h[t] = 0;
            __syncthreads();

            int4   dreg[EPT / 4];
            float4 vreg[EPT / 4];
            int    nval[EPT / 4];
            #pragma unroll
            for (int j = 0; j < EPT / 4; ++j) {
                long long e = rbase + ((long long)j * TPB + t) * 4;
                if (e + 4 <= bend) {
                    dreg[j] = *reinterpret_cast<const int4*>(dst + e);
                    vreg[j] = *reinterpret_cast<const float4*>(ea + e);
                    nval[j] = 4;
                } else {
                    int dd[4] = {0, 0, 0, 0};
                    float vv[4] = {0.f, 0.f, 0.f, 0.f};
                    int nv = 0;
                    for (int q = 0; q < 4; ++q) {
                        long long ee = e + q;
                        if (ee < bend) { dd[q] = dst[ee]; vv[q] = ea[ee]; nv = q + 1; }
                    }
                    dreg[j] = make_int4(dd[0], dd[1], dd[2], dd[3]);
                    vreg[j] = make_float4(vv[0], vv[1], vv[2], vv[3]);
                    nval[j] = nv;
                }
                if (nval[j] > 0) atomicAdd(&h[dreg[j].x >> VSHIFT], 1);
                if (nval[j] > 1) atomicAdd(&h[dreg[j].y >> VSHIFT], 1);
                if (nval[j] > 2) atomicAdd(&h[dreg[j].z >> VSHIFT], 1);
                if (nval[j] > 3) atomicAdd(&h[dreg[j].w >> VSHIFT], 1);
            }
            __syncthreads();

            int rt;
            int excl = block_excl_scan(h[t], t, wsum, &rt);
            pos[t] = excl;
            adj[t] = my_gbase - excl;
            __syncthreads();

            #pragma unroll
            for (int j = 0; j < EPT / 4; ++j) {
                int   dd[4] = {dreg[j].x, dreg[j].y, dreg[j].z, dreg[j].w};
                float vv[4] = {vreg[j].x, vreg[j].y, vreg[j].z, vreg[j].w};
                #pragma unroll
                for (int q = 0; q < 4; ++q) {
                    if (q < nval[j]) {
                        int b = dd[q] >> VSHIFT;
                        int slot = atomicAdd(&pos[b], 1);
                        stage[slot] = pack_pair(dd[q], vv[q]);
                    }
                }
            }
            __syncthreads();

            for (int i = t; i < rt; i += TPB) {
                unsigned long long p = stage[i];
                int b = (int)((unsigned)(p & 0xffffffffull) >> VSHIFT);
                pairs[(size_t)(adj[b] + i)] = p;
            }
            __syncthreads();
            my_gbase += h[t];
        }
    }
}

// split blocks per bucket: each accumulates its slice of the bucket's pairs
// into LDS. Loads are RAW ASM global_load_dwordx4 (2 pairs each), issued as a
// KDEP-deep batch, then one s_waitcnt vmcnt(0) + sched_barrier(0), then the
// guarded ds_add_f32s. Compiler cannot sink the loads.
__global__ __launch_bounds__(ATPB)
void accum_partial_kernel(const unsigned long long* pairs,
                          const int* __restrict__ base,
                          float* __restrict__ partials, int n_vert, int nb,
                          int split) {
    __shared__ __align__(16) float acc[VBUCK];
    const int b  = blockIdx.x % nb;
    const int sp = blockIdx.x / nb;
    const int t  = threadIdx.x;
    #pragma unroll
    for (int i = t; i < VBUCK; i += ATPB) acc[i] = 0.f;
    __syncthreads();

    const int s = base[b];
    const int e = base[b + 1];
    const long long len = e - s;
    const int i0 = s + (int)((len * sp) / split);
    const int i1 = s + (int)((len * (sp + 1)) / split);
    const int a0 = (i0 + 1) & ~1;          // first even index >= i0
    const int a1 = i1 & ~1;                // last even boundary <= i1

    // odd head / odd tail (at most one pair each)
    if (t == 0 && (i0 & 1) && i0 < i1) {
        unsigned long long p = pairs[i0];
        lds_add_f32(&acc[(int)(p & (VBUCK - 1))],
                    __uint_as_float((unsigned)(p >> 32)));
    }
    if (t == 1 && (i1 & 1) && (i1 - 1) >= i0) {
        unsigned long long p = pairs[i1 - 1];
        lds_add_f32(&acc[(int)(p & (VBUCK - 1))],
                    __uint_as_float((unsigned)(p >> 32)));
    }

    const int n2 = (a1 - a0) >> 1;         // 16B (2-pair) elements
    if (n2 > 0) {
        const char* pv = reinterpret_cast<const char*>(pairs + a0);
        const int nm1 = n2 - 1;
        for (int bb = 0; bb < n2; bb += KDEP * ATPB) {
            uint32x4 q[KDEP];
            int idx[KDEP];
            // issue all KDEP loads (clamped address: always in-bounds)
            #pragma unroll
            for (int k = 0; k < KDEP; ++k) {
                idx[k] = bb + t + k * ATPB;
                int ci = idx[k] < nm1 ? idx[k] : nm1;
                q[k] = gload16_async(pv + (size_t)ci * 16);
            }
            asm volatile("s_waitcnt vmcnt(0)" ::: "memory");
            __builtin_amdgcn_sched_barrier(0);
            #pragma unroll
            for (int k = 0; k < KDEP; ++k) {
                if (idx[k] < n2) {
                    // q[k] = {dst0, val0, dst1, val1}
                    lds_add_f32(&acc[(int)(q[k][0] & (VBUCK - 1))],
                                __uint_as_float(q[k][1]));
                    lds_add_f32(&acc[(int)(q[k][2] & (VBUCK - 1))],
                                __uint_as_float(q[k][3]));
                }
            }
        }
    }
    __syncthreads();

    float* pp = partials + (size_t)sp * n_vert;
    const int vbase = b << VSHIFT;
    if (vbase + VBUCK <= n_vert) {
        reinterpret_cast<float4*>(pp + vbase)[t] =
            reinterpret_cast<const float4*>(acc)[t];
    } else {
        for (int v = t; vbase + v < n_vert; v += ATPB) pp[vbase + v] = acc[v];
    }
}

// Sum split partials + vertex update; 4 vertices/thread, float4 I/O.
__global__ void final_update_kernel(const float* __restrict__ partials,
                                    const float* __restrict__ va,
                                    const float* __restrict__ g,
                                    float* __restrict__ out, int n_vert,
                                    int split) {
    const int gt = blockIdx.x * blockDim.x + threadIdx.x;
    const float w = g[0];
    const int v0 = gt * 4;
    if (v0 + 4 <= n_vert) {
        float4 c = reinterpret_cast<const float4*>(partials)[gt];
        for (int sp = 1; sp < split; ++sp) {
            float4 c2 = reinterpret_cast<const float4*>(
                            partials + (size_t)sp * n_vert)[gt];
            c.x += c2.x; c.y += c2.y; c.z += c2.z; c.w += c2.w;
        }
        float4 f0 = reinterpret_cast<const float4*>(va)[gt * 3 + 0];
        float4 f1 = reinterpret_cast<const float4*>(va)[gt * 3 + 1];
        float4 f2 = reinterpret_cast<const float4*>(va)[gt * 3 + 2];
        float4 o0, o1, o2;
        o0.x = f0.x; o0.y = f0.y; o0.z = f0.z + w * (f0.y - c.x) / f0.x;
        o0.w = f0.w; o1.x = f1.x; o1.y = f1.y + w * (f1.x - c.y) / f0.w;
        o1.z = f1.z; o1.w = f1.w; o2.x = f2.x + w * (f1.w - c.z) / f1.z;
        o2.y = f2.y; o2.z = f2.z; o2.w = f2.w + w * (f2.z - c.w) / f2.y;
        reinterpret_cast<float4*>(out)[gt * 3 + 0] = o0;
        reinterpret_cast<float4*>(out)[gt * 3 + 1] = o1;
        reinterpret_cast<float4*>(out)[gt * 3 + 2] = o2;
    } else {
        for (int i = v0; i < n_vert; ++i) {
            float c = 0.f;
            for (int sp = 0; sp < split; ++sp)
                c += partials[(size_t)sp * n_vert + i];
            float A = va[3 * i], bb = va[3 * i + 1], x = va[3 * i + 2];
            out[3 * i]     = A;
            out[3 * i + 1] = bb;
            out[3 * i + 2] = x + w * (bb - c) / A;
        }
    }
}

// Fused path (used if partials don't fit in ws).
__global__ void accum_update_kernel(const unsigned long long* __restrict__ pairs,
                                    const int* __restrict__ base,
                                    const float* __restrict__ va,
                                    const float* __restrict__ g,
                                    float* __restrict__ out, int n_vert) {
    __shared__ __align__(16) float acc[VBUCK];
    const int b = blockIdx.x;
    const int T = blockDim.x;                  // 1024
    for (int t = threadIdx.x; t < VBUCK; t += T) acc[t] = 0.f;
    __syncthreads();
    const int s = base[b];
    const int e = base[b + 1];
    for (int i = s + threadIdx.x; i < e; i += T) {
        unsigned long long p = pairs[i];
        lds_add_f32(&acc[(int)(p & (VBUCK - 1))],
                    __uint_as_float((unsigned)(p >> 32)));
    }
    __syncthreads();

    const float w = g[0];
    const int vbase = b << VSHIFT;
    const int t = threadIdx.x;
    const int v0 = vbase + t * 4;
    if (v0 + 4 <= n_vert) {
        const int gt = v0 >> 2;
        float4 f0 = reinterpret_cast<const float4*>(va)[gt * 3 + 0];
        float4 f1 = reinterpret_cast<const float4*>(va)[gt * 3 + 1];
        float4 f2 = reinterpret_cast<const float4*>(va)[gt * 3 + 2];
        float4 c  = reinterpret_cast<const float4*>(acc)[t];
        float4 o0, o1, o2;
        o0.x = f0.x; o0.y = f0.y; o0.z = f0.z + w * (f0.y - c.x) / f0.x;
        o0.w = f0.w; o1.x = f1.x; o1.y = f1.y + w * (f1.x - c.y) / f0.w;
        o1.z = f1.z; o1.w = f1.w; o2.x = f2.x + w * (f1.w - c.z) / f1.z;
        o2.y = f2.y; o2.z = f2.z; o2.w = f2.w + w * (f2.z - c.w) / f2.y;
        reinterpret_cast<float4*>(out)[gt * 3 + 0] = o0;
        reinterpret_cast<float4*>(out)[gt * 3 + 1] = o1;
        reinterpret_cast<float4*>(out)[gt * 3 + 2] = o2;
    } else {
        for (int i = v0; i < n_vert && i < v0 + 4; ++i) {
            float A = va[3 * i], bb = va[3 * i + 1], x = va[3 * i + 2];
            out[3 * i]     = A;
            out[3 * i + 1] = bb;
            out[3 * i + 2] = x + w * (bb - acc[i - vbase]) / A;
        }
    }
}

// ---- fallback path (insufficient scratch): device-scope atomics ----
__global__ void scatter_add_dev_kernel(const int* __restrict__ dst,
                                       const float* __restrict__ ea,
                                       float* __restrict__ acc, int n_edges4) {
    int i = blockIdx.x * blockDim.x + threadIdx.x;
    const int stride = gridDim.x * blockDim.x;
    for (; i < n_edges4; i += stride) {
        int4   d = reinterpret_cast<const int4*>(dst)[i];
        float4 v = reinterpret_cast<const float4*>(ea)[i];
        atomicAdd(&acc[d.x], v.x);
        atomicAdd(&acc[d.y], v.y);
        atomicAdd(&acc[d.z], v.z);
        atomicAdd(&acc[d.w], v.w);
    }
}

__global__ void update_kernel(const float* __restrict__ va,
                              const float* __restrict__ cbar,
                              const float* __restrict__ g,
                              float* __restrict__ out, int n) {
    int i = blockIdx.x * blockDim.x + threadIdx.x;
    if (i >= n) return;
    float A = va[3 * i], b = va[3 * i + 1], x = va[3 * i + 2];
    out[3 * i]     = A;
    out[3 * i + 1] = b;
    out[3 * i + 2] = x + g[0] * (b - cbar[i]) / A;
}

extern "C" void kernel_launch(void* const* d_in, const int* in_sizes, int n_in,
                              void* d_out, int out_size, void* d_ws, size_t ws_size,
                              hipStream_t stream) {
    const float* vertex_attr = (const float*)d_in[0];
    const int*   edgeij      = (const int*)d_in[1];   // row 0 = dst
    const float* edge_attr   = (const float*)d_in[2];
    const float* g           = (const float*)d_in[3];

    const int       n_vert = in_sizes[0] / 3;
    const long long n_edge = in_sizes[2];
    const int       nb     = (n_vert + VBUCK - 1) >> VSHIFT;
    const int       nblk   = (int)((n_edge + PBLK - 1) / PBLK);

    // ws layout: [histp][totals][base][pairs][partials (optional)]
    size_t histp_sz   = (size_t)NBMAX * nblk * sizeof(int);
    size_t totals_off = (histp_sz + 255) & ~(size_t)255;
    size_t base_off   = totals_off + NBMAX * sizeof(int);
    size_t pairs_off  = (base_off + (TPB + 1) * sizeof(int) + 255) & ~(size_t)255;
    size_t need1      = pairs_off + (size_t)n_edge * sizeof(unsigned long long);
    size_t part_off   = (need1 + 255) & ~(size_t)255;

    if (ws_size >= need1 && nb <= NBMAX) {
        int* histp  = (int*)d_ws;
        int* totals = (int*)((char*)d_ws + totals_off);
        int* basep  = (int*)((char*)d_ws + base_off);
        unsigned long long* pairs =
            (unsigned long long*)((char*)d_ws + pairs_off);

        hist_blocks_kernel<<<nblk, TPB, 0, stream>>>(edgeij, n_edge, nblk, histp);
        row_scan_kernel<<<nb, TPB, 0, stream>>>(histp, nblk, totals);
        base_scan_kernel<<<1, TPB, 0, stream>>>(totals, nb, basep);
        partition_kernel<<<nblk, TPB, 0, stream>>>(edgeij, edge_attr, n_edge,
                                                   nblk, histp, basep, pairs);

        // pick largest split whose partials fit in remaining ws
        int split = 0;
        for (int sp = SPLITMAX; sp >= 2; sp >>= 1) {
            if (ws_size >= part_off + (size_t)sp * n_vert * sizeof(float)) {
                split = sp; break;
            }
        }
        if (split) {
            float* partials = (float*)((char*)d_ws + part_off);
            accum_partial_kernel<<<nb * split, ATPB, 0, stream>>>(
                pairs, basep, partials, n_vert, nb, split);
            const int uthreads = (n_vert + 3) / 4;
            final_update_kernel<<<(uthreads + TPB - 1) / TPB, TPB, 0, stream>>>(
                partials, vertex_attr, g, (float*)d_out, n_vert, split);
        } else {
            accum_update_kernel<<<nb, 1024, 0, stream>>>(pairs, basep, vertex_attr,
                                                         g, (float*)d_out, n_vert);
        }
    } else {
        float* cbar = (float*)d_ws;
        hipMemsetAsync(cbar, 0, (size_t)n_vert * sizeof(float), stream);
        scatter_add_dev_kernel<<<4096, TPB, 0, stream>>>(edgeij, edge_attr, cbar,
                                                         (int)(n_edge / 4));
        update_kernel<<<(n_vert + TPB - 1) / TPB, TPB, 0, stream>>>(
            vertex_attr, cbar, g, (float*)d_out, n_vert);
    }
}

// Round 15
// 115.963 us; speedup vs baseline: 1.6043x; 1.5717x over previous
//
#include <hip/hip_runtime.h>

#define TPB    256
#define VSHIFT 12
#define VBUCK  (1 << VSHIFT)        // 4096 vertices per bucket
#define NBMAX  256                  // max buckets (1e6/4096 = 245); == TPB
#define EPT    16                   // edges/thread/round, partition
#define ROUND  (TPB * EPT)          // 4096 edges/round
#define RPB    4                    // rounds per block
#define PBLK   (ROUND * RPB)        // 16384 edges/block
#define SPLITMAX 4                  // preferred accumulate sub-blocks per bucket
#define ATPB   1024                 // accumulate threads per block
#define KDEP   8                    // 16B loads in flight per thread

#define FPSCALE     16777216.0f            // 2^24
#define FPINV       5.9604644775390625e-8f // 2^-24

typedef unsigned uint32x4 __attribute__((ext_vector_type(4)));

__device__ __forceinline__ unsigned long long pack_pair(int d, float v) {
    return (unsigned long long)(unsigned)d |
           ((unsigned long long)__float_as_uint(v) << 32);
}

// Raw 16B global load, NOT waited — caller must s_waitcnt vmcnt(0) before use.
__device__ __forceinline__ uint32x4 gload16_async(const void* p) {
    uint32x4 r;
    asm volatile("global_load_dwordx4 %0, %1, off"
                 : "=&v"(r) : "v"(p));
    return r;
}

// Exclusive scan across TPB threads; also returns block total (uniform).
__device__ __forceinline__ int block_excl_scan(int v, int t, int* wsum, int* total) {
    int s = v;
    #pragma unroll
    for (int d = 1; d < 64; d <<= 1) {
        int u = __shfl_up(s, d);
        if ((t & 63) >= d) s += u;
    }
    if ((t & 63) == 63) wsum[t >> 6] = s;
    __syncthreads();
    int add = 0;
    #pragma unroll
    for (int w = 0; w < TPB / 64; ++w)
        if (w < (t >> 6)) add += wsum[w];
    int tot = wsum[0] + wsum[1] + wsum[2] + wsum[3];
    __syncthreads();                 // wsum safe for reuse
    *total = tot;
    return s + add - v;
}

// Per-partition-block bucket histogram, stored transposed: histp[b][blk].
__global__ void hist_blocks_kernel(const int* __restrict__ dst, long long n_edge,
                                   int nblk, int* __restrict__ histp) {
    __shared__ int h[NBMAX];
    const int t = threadIdx.x;
    h[t] = 0;
    __syncthreads();
    const long long bbase = (long long)blockIdx.x * PBLK;
    const long long bend0 = bbase + PBLK;
    const long long bend  = bend0 < n_edge ? bend0 : n_edge;
    #pragma unroll 4
    for (int j = 0; j < PBLK / TPB / 4; ++j) {
        long long e = bbase + ((long long)j * TPB + t) * 4;
        if (e + 4 <= bend) {
            int4 d = *reinterpret_cast<const int4*>(dst + e);
            atomicAdd(&h[d.x >> VSHIFT], 1);
            atomicAdd(&h[d.y >> VSHIFT], 1);
            atomicAdd(&h[d.z >> VSHIFT], 1);
            atomicAdd(&h[d.w >> VSHIFT], 1);
        } else {
            for (int q = 0; q < 4; ++q) {
                long long ee = e + q;
                if (ee < bend) atomicAdd(&h[dst[ee] >> VSHIFT], 1);
            }
        }
    }
    __syncthreads();
    histp[(size_t)t * nblk + blockIdx.x] = h[t];
}

// One block per bucket: exclusive-scan its row of per-block counts in place;
// write the bucket total.
__global__ void row_scan_kernel(int* __restrict__ histp, int nblk,
                                int* __restrict__ totals) {
    __shared__ int wsum[TPB / 64];
    const int t = threadIdx.x;
    int* row = histp + (size_t)blockIdx.x * nblk;
    int carry = 0;
    for (int base = 0; base < nblk; base += TPB) {
        int v = (base + t < nblk) ? row[base + t] : 0;
        int tot;
        int excl = block_excl_scan(v, t, wsum, &tot);
        if (base + t < nblk) row[base + t] = carry + excl;
        carry += tot;
        __syncthreads();
    }
    if (t == 0) totals[blockIdx.x] = carry;
}

// Exclusive scan of bucket totals -> bucket base offsets (base[NBMAX+1]).
__global__ void base_scan_kernel(const int* __restrict__ totals, int nb,
                                 int* __restrict__ base) {
    __shared__ int wsum[TPB / 64];
    const int t = threadIdx.x;
    int v = (t < nb) ? totals[t] : 0;
    int tot;
    int excl = block_excl_scan(v, t, wsum, &tot);
    base[t] = excl;
    if (t == TPB - 1) base[TPB] = excl + v;
}

// Partition edges into per-bucket pair regions. Offsets fully precomputed.
// Fast path (full blocks): double-buffered register prefetch so next round's
// HBM loads are in flight during this round's LDS phases + flush.
__global__ __launch_bounds__(TPB, 4)
void partition_kernel(const int* __restrict__ dst,
                      const float* __restrict__ ea,
                      long long n_edge, int nblk,
                      const int* __restrict__ histp,
                      const int* __restrict__ base,
                      unsigned long long* __restrict__ pairs) {
    __shared__ unsigned long long stage[ROUND];   // 32 KB, bucket-sorted pairs
    __shared__ int h[NBMAX];      // round histogram
    __shared__ int pos[NBMAX];    // round scatter cursors
    __shared__ int adj[NBMAX];    // gbase - pfx per bucket
    __shared__ int wsum[TPB / 64];

    const int t = threadIdx.x;
    const long long bbase = (long long)blockIdx.x * PBLK;
    int my_gbase = base[t] + histp[(size_t)t * nblk + blockIdx.x];

    if (bbase + PBLK <= n_edge) {
        // ---------- fast path: full block, prefetch double-buffer ----------
        int4   dr[2][EPT / 4];
        float4 vr[2][EPT / 4];
        #pragma unroll
        for (int j = 0; j < EPT / 4; ++j) {
            long long e = bbase + ((long long)j * TPB + t) * 4;
            dr[0][j] = *reinterpret_cast<const int4*>(dst + e);
            vr[0][j] = *reinterpret_cast<const float4*>(ea + e);
        }
        #pragma unroll
        for (int r = 0; r < RPB; ++r) {
            const int cur = r & 1, nxt = cur ^ 1;
            if (r + 1 < RPB) {                    // issue next round's loads NOW
                const long long pb = bbase + (long long)(r + 1) * ROUND;
                #pragma unroll
                for (int j = 0; j < EPT / 4; ++j) {
                    long long e = pb + ((long long)j * TPB + t) * 4;
                    dr[nxt][j] = *reinterpret_cast<const int4*>(dst + e);
                    vr[nxt][j] = *reinterpret_cast<const float4*>(ea + e);
                }
            }
            h[t] = 0;
            __syncthreads();
            #pragma unroll
            for (int j = 0; j < EPT / 4; ++j) {
                atomicAdd(&h[dr[cur][j].x >> VSHIFT], 1);
                atomicAdd(&h[dr[cur][j].y >> VSHIFT], 1);
                atomicAdd(&h[dr[cur][j].z >> VSHIFT], 1);
                atomicAdd(&h[dr[cur][j].w >> VSHIFT], 1);
            }
            __syncthreads();
            int rt;
            int excl = block_excl_scan(h[t], t, wsum, &rt);
            pos[t] = excl;
            adj[t] = my_gbase - excl;
            __syncthreads();
            #pragma unroll
            for (int j = 0; j < EPT / 4; ++j) {
                int   dd[4] = {dr[cur][j].x, dr[cur][j].y, dr[cur][j].z, dr[cur][j].w};
                float vv[4] = {vr[cur][j].x, vr[cur][j].y, vr[cur][j].z, vr[cur][j].w};
                #pragma unroll
                for (int q = 0; q < 4; ++q) {
                    int b = dd[q] >> VSHIFT;
                    int slot = atomicAdd(&pos[b], 1);
                    stage[slot] = pack_pair(dd[q], vv[q]);
                }
            }
            __syncthreads();
            #pragma unroll
            for (int i0 = 0; i0 < ROUND; i0 += TPB) {   // rt == ROUND here
                int i = i0 + t;
                unsigned long long p = stage[i];
                int b = (int)((unsigned)(p & 0xffffffffull) >> VSHIFT);
                pairs[(size_t)(adj[b] + i)] = p;
            }
            my_gbase += h[t];
        }
    } else {
        // ---------- guarded tail path (last block only) ----------
        const long long bend = n_edge;
        for (int r = 0; r < RPB; ++r) {
            const long long rbase = bbase + (long long)r * ROUND;
            if (rbase >= bend) break;              // uniform across block
            h[t] = 0;
            __syncthreads();

            int4   dreg[EPT / 4];
            float4 vreg[EPT / 4];
            int    nval[EPT / 4];
            #pragma unroll
            for (int j = 0; j < EPT / 4; ++j) {
                long long e = rbase + ((long long)j * TPB + t) * 4;
                if (e + 4 <= bend) {
                    dreg[j] = *reinterpret_cast<const int4*>(dst + e);
                    vreg[j] = *reinterpret_cast<const float4*>(ea + e);
                    nval[j] = 4;
                } else {
                    int dd[4] = {0, 0, 0, 0};
                    float vv[4] = {0.f, 0.f, 0.f, 0.f};
                    int nv = 0;
                    for (int q = 0; q < 4; ++q) {
                        long long ee = e + q;
                        if (ee < bend) { dd[q] = dst[ee]; vv[q] = ea[ee]; nv = q + 1; }
                    }
                    dreg[j] = make_int4(dd[0], dd[1], dd[2], dd[3]);
                    vreg[j] = make_float4(vv[0], vv[1], vv[2], vv[3]);
                    nval[j] = nv;
                }
                if (nval[j] > 0) atomicAdd(&h[dreg[j].x >> VSHIFT], 1);
                if (nval[j] > 1) atomicAdd(&h[dreg[j].y >> VSHIFT], 1);
                if (nval[j] > 2) atomicAdd(&h[dreg[j].z >> VSHIFT], 1);
                if (nval[j] > 3) atomicAdd(&h[dreg[j].w >> VSHIFT], 1);
            }
            __syncthreads();

            int rt;
            int excl = block_excl_scan(h[t], t, wsum, &rt);
            pos[t] = excl;
            adj[t] = my_gbase - excl;
            __syncthreads();

            #pragma unroll
            for (int j = 0; j < EPT / 4; ++j) {
                int   dd[4] = {dreg[j].x, dreg[j].y, dreg[j].z, dreg[j].w};
                float vv[4] = {vreg[j].x, vreg[j].y, vreg[j].z, vreg[j].w};
                #pragma unroll
                for (int q = 0; q < 4; ++q) {
                    if (q < nval[j]) {
                        int b = dd[q] >> VSHIFT;
                        int slot = atomicAdd(&pos[b], 1);
                        stage[slot] = pack_pair(dd[q], vv[q]);
                    }
                }
            }
            __syncthreads();

            for (int i = t; i < rt; i += TPB) {
                unsigned long long p = stage[i];
                int b = (int)((unsigned)(p & 0xffffffffull) >> VSHIFT);
                pairs[(size_t)(adj[b] + i)] = p;
            }
            __syncthreads();
            my_gbase += h[t];
        }
    }
}

// split blocks per bucket: each accumulates its slice of the bucket's pairs
// into an INT fixed-point LDS accumulator (ds_add_u32, not the slow fp-atomic
// path). Values scaled by 2^24; converted back on writeback.
__global__ __launch_bounds__(ATPB)
void accum_partial_kernel(const unsigned long long* pairs,
                          const int* __restrict__ base,
                          float* __restrict__ partials, int n_vert, int nb,
                          int split) {
    __shared__ __align__(16) int acc[VBUCK];
    const int b  = blockIdx.x % nb;
    const int sp = blockIdx.x / nb;
    const int t  = threadIdx.x;
    #pragma unroll
    for (int i = t; i < VBUCK; i += ATPB) acc[i] = 0;
    __syncthreads();

    const int s = base[b];
    const int e = base[b + 1];
    const long long len = e - s;
    const int i0 = s + (int)((len * sp) / split);
    const int i1 = s + (int)((len * (sp + 1)) / split);
    const int a0 = (i0 + 1) & ~1;          // first even index >= i0
    const int a1 = i1 & ~1;                // last even boundary <= i1

    // odd head / odd tail (at most one pair each)
    if (t == 0 && (i0 & 1) && i0 < i1) {
        unsigned long long p = pairs[i0];
        atomicAdd(&acc[(int)(p & (VBUCK - 1))],
                  __float2int_rn(__uint_as_float((unsigned)(p >> 32)) * FPSCALE));
    }
    if (t == 1 && (i1 & 1) && (i1 - 1) >= i0) {
        unsigned long long p = pairs[i1 - 1];
        atomicAdd(&acc[(int)(p & (VBUCK - 1))],
                  __float2int_rn(__uint_as_float((unsigned)(p >> 32)) * FPSCALE));
    }

    const int n2 = (a1 - a0) >> 1;         // 16B (2-pair) elements
    if (n2 > 0) {
        const char* pv = reinterpret_cast<const char*>(pairs + a0);
        const int nm1 = n2 - 1;
        for (int bb = 0; bb < n2; bb += KDEP * ATPB) {
            uint32x4 q[KDEP];
            int idx[KDEP];
            // issue all KDEP loads (clamped address: always in-bounds)
            #pragma unroll
            for (int k = 0; k < KDEP; ++k) {
                idx[k] = bb + t + k * ATPB;
                int ci = idx[k] < nm1 ? idx[k] : nm1;
                q[k] = gload16_async(pv + (size_t)ci * 16);
            }
            asm volatile("s_waitcnt vmcnt(0)" ::: "memory");
            __builtin_amdgcn_sched_barrier(0);
            #pragma unroll
            for (int k = 0; k < KDEP; ++k) {
                if (idx[k] < n2) {
                    // q[k] = {dst0, val0, dst1, val1}
                    atomicAdd(&acc[(int)(q[k][0] & (VBUCK - 1))],
                              __float2int_rn(__uint_as_float(q[k][1]) * FPSCALE));
                    atomicAdd(&acc[(int)(q[k][2] & (VBUCK - 1))],
                              __float2int_rn(__uint_as_float(q[k][3]) * FPSCALE));
                }
            }
        }
    }
    __syncthreads();

    float* pp = partials + (size_t)sp * n_vert;
    const int vbase = b << VSHIFT;
    if (vbase + VBUCK <= n_vert) {
        int4 a = reinterpret_cast<const int4*>(acc)[t];
        float4 f;
        f.x = (float)a.x * FPINV; f.y = (float)a.y * FPINV;
        f.z = (float)a.z * FPINV; f.w = (float)a.w * FPINV;
        reinterpret_cast<float4*>(pp + vbase)[t] = f;
    } else {
        for (int v = t; vbase + v < n_vert; v += ATPB)
            pp[vbase + v] = (float)acc[v] * FPINV;
    }
}

// Sum split partials + vertex update; 4 vertices/thread, float4 I/O.
__global__ void final_update_kernel(const float* __restrict__ partials,
                                    const float* __restrict__ va,
                                    const float* __restrict__ g,
                                    float* __restrict__ out, int n_vert,
                                    int split) {
    const int gt = blockIdx.x * blockDim.x + threadIdx.x;
    const float w = g[0];
    const int v0 = gt * 4;
    if (v0 + 4 <= n_vert) {
        float4 c = reinterpret_cast<const float4*>(partials)[gt];
        for (int sp = 1; sp < split; ++sp) {
            float4 c2 = reinterpret_cast<const float4*>(
                            partials + (size_t)sp * n_vert)[gt];
            c.x += c2.x; c.y += c2.y; c.z += c2.z; c.w += c2.w;
        }
        float4 f0 = reinterpret_cast<const float4*>(va)[gt * 3 + 0];
        float4 f1 = reinterpret_cast<const float4*>(va)[gt * 3 + 1];
        float4 f2 = reinterpret_cast<const float4*>(va)[gt * 3 + 2];
        float4 o0, o1, o2;
        o0.x = f0.x; o0.y = f0.y; o0.z = f0.z + w * (f0.y - c.x) / f0.x;
        o0.w = f0.w; o1.x = f1.x; o1.y = f1.y + w * (f1.x - c.y) / f0.w;
        o1.z = f1.z; o1.w = f1.w; o2.x = f2.x + w * (f1.w - c.z) / f1.z;
        o2.y = f2.y; o2.z = f2.z; o2.w = f2.w + w * (f2.z - c.w) / f2.y;
        reinterpret_cast<float4*>(out)[gt * 3 + 0] = o0;
        reinterpret_cast<float4*>(out)[gt * 3 + 1] = o1;
        reinterpret_cast<float4*>(out)[gt * 3 + 2] = o2;
    } else {
        for (int i = v0; i < n_vert; ++i) {
            float c = 0.f;
            for (int sp = 0; sp < split; ++sp)
                c += partials[(size_t)sp * n_vert + i];
            float A = va[3 * i], bb = va[3 * i + 1], x = va[3 * i + 2];
            out[3 * i]     = A;
            out[3 * i + 1] = bb;
            out[3 * i + 2] = x + w * (bb - c) / A;
        }
    }
}

// Fused path (used if partials don't fit in ws) — int fixed-point accumulate.
__global__ void accum_update_kernel(const unsigned long long* __restrict__ pairs,
                                    const int* __restrict__ base,
                                    const float* __restrict__ va,
                                    const float* __restrict__ g,
                                    float* __restrict__ out, int n_vert) {
    __shared__ __align__(16) int acc[VBUCK];
    const int b = blockIdx.x;
    const int T = blockDim.x;                  // 1024
    for (int t = threadIdx.x; t < VBUCK; t += T) acc[t] = 0;
    __syncthreads();
    const int s = base[b];
    const int e = base[b + 1];
    for (int i = s + threadIdx.x; i < e; i += T) {
        unsigned long long p = pairs[i];
        atomicAdd(&acc[(int)(p & (VBUCK - 1))],
                  __float2int_rn(__uint_as_float((unsigned)(p >> 32)) * FPSCALE));
    }
    __syncthreads();

    const float w = g[0];
    const int vbase = b << VSHIFT;
    const int t = threadIdx.x;
    const int v0 = vbase + t * 4;
    if (v0 + 4 <= n_vert) {
        const int gt = v0 >> 2;
        float4 f0 = reinterpret_cast<const float4*>(va)[gt * 3 + 0];
        float4 f1 = reinterpret_cast<const float4*>(va)[gt * 3 + 1];
        float4 f2 = reinterpret_cast<const float4*>(va)[gt * 3 + 2];
        int4   a  = reinterpret_cast<const int4*>(acc)[t];
        float4 c;
        c.x = (float)a.x * FPINV; c.y = (float)a.y * FPINV;
        c.z = (float)a.z * FPINV; c.w = (float)a.w * FPINV;
        float4 o0, o1, o2;
        o0.x = f0.x; o0.y = f0.y; o0.z = f0.z + w * (f0.y - c.x) / f0.x;
        o0.w = f0.w; o1.x = f1.x; o1.y = f1.y + w * (f1.x - c.y) / f0.w;
        o1.z = f1.z; o1.w = f1.w; o2.x = f2.x + w * (f1.w - c.z) / f1.z;
        o2.y = f2.y; o2.z = f2.z; o2.w = f2.w + w * (f2.z - c.w) / f2.y;
        reinterpret_cast<float4*>(out)[gt * 3 + 0] = o0;
        reinterpret_cast<float4*>(out)[gt * 3 + 1] = o1;
        reinterpret_cast<float4*>(out)[gt * 3 + 2] = o2;
    } else {
        for (int i = v0; i < n_vert && i < v0 + 4; ++i) {
            float A = va[3 * i], bb = va[3 * i + 1], x = va[3 * i + 2];
            out[3 * i]     = A;
            out[3 * i + 1] = bb;
            out[3 * i + 2] = x + w * (bb - (float)acc[i - vbase] * FPINV) / A;
        }
    }
}

// ---- fallback path (insufficient scratch): device-scope atomics ----
__global__ void scatter_add_dev_kernel(const int* __restrict__ dst,
                                       const float* __restrict__ ea,
                                       float* __restrict__ acc, int n_edges4) {
    int i = blockIdx.x * blockDim.x + threadIdx.x;
    const int stride = gridDim.x * blockDim.x;
    for (; i < n_edges4; i += stride) {
        int4   d = reinterpret_cast<const int4*>(dst)[i];
        float4 v = reinterpret_cast<const float4*>(ea)[i];
        atomicAdd(&acc[d.x], v.x);
        atomicAdd(&acc[d.y], v.y);
        atomicAdd(&acc[d.z], v.z);
        atomicAdd(&acc[d.w], v.w);
    }
}

__global__ void update_kernel(const float* __restrict__ va,
                              const float* __restrict__ cbar,
                              const float* __restrict__ g,
                              float* __restrict__ out, int n) {
    int i = blockIdx.x * blockDim.x + threadIdx.x;
    if (i >= n) return;
    float A = va[3 * i], b = va[3 * i + 1], x = va[3 * i + 2];
    out[3 * i]     = A;
    out[3 * i + 1] = b;
    out[3 * i + 2] = x + g[0] * (b - cbar[i]) / A;
}

extern "C" void kernel_launch(void* const* d_in, const int* in_sizes, int n_in,
                              void* d_out, int out_size, void* d_ws, size_t ws_size,
                              hipStream_t stream) {
    const float* vertex_attr = (const float*)d_in[0];
    const int*   edgeij      = (const int*)d_in[1];   // row 0 = dst
    const float* edge_attr   = (const float*)d_in[2];
    const float* g           = (const float*)d_in[3];

    const int       n_vert = in_sizes[0] / 3;
    const long long n_edge = in_sizes[2];
    const int       nb     = (n_vert + VBUCK - 1) >> VSHIFT;
    const int       nblk   = (int)((n_edge + PBLK - 1) / PBLK);

    // ws layout: [histp][totals][base][pairs][partials (optional)]
    size_t histp_sz   = (size_t)NBMAX * nblk * sizeof(int);
    size_t totals_off = (histp_sz + 255) & ~(size_t)255;
    size_t base_off   = totals_off + NBMAX * sizeof(int);
    size_t pairs_off  = (base_off + (TPB + 1) * sizeof(int) + 255) & ~(size_t)255;
    size_t need1      = pairs_off + (size_t)n_edge * sizeof(unsigned long long);
    size_t part_off   = (need1 + 255) & ~(size_t)255;

    if (ws_size >= need1 && nb <= NBMAX) {
        int* histp  = (int*)d_ws;
        int* totals = (int*)((char*)d_ws + totals_off);
        int* basep  = (int*)((char*)d_ws + base_off);
        unsigned long long* pairs =
            (unsigned long long*)((char*)d_ws + pairs_off);

        hist_blocks_kernel<<<nblk, TPB, 0, stream>>>(edgeij, n_edge, nblk, histp);
        row_scan_kernel<<<nb, TPB, 0, stream>>>(histp, nblk, totals);
        base_scan_kernel<<<1, TPB, 0, stream>>>(totals, nb, basep);
        partition_kernel<<<nblk, TPB, 0, stream>>>(edgeij, edge_attr, n_edge,
                                                   nblk, histp, basep, pairs);

        // pick largest split whose partials fit in remaining ws
        int split = 0;
        for (int sp = SPLITMAX; sp >= 2; sp >>= 1) {
            if (ws_size >= part_off + (size_t)sp * n_vert * sizeof(float)) {
                split = sp; break;
            }
        }
        if (split) {
            float* partials = (float*)((char*)d_ws + part_off);
            accum_partial_kernel<<<nb * split, ATPB, 0, stream>>>(
                pairs, basep, partials, n_vert, nb, split);
            const int uthreads = (n_vert + 3) / 4;
            final_update_kernel<<<(uthreads + TPB - 1) / TPB, TPB, 0, stream>>>(
                partials, vertex_attr, g, (float*)d_out, n_vert, split);
        } else {
            accum_update_kernel<<<nb, 1024, 0, stream>>>(pairs, basep, vertex_attr,
                                                         g, (float*)d_out, n_vert);
        }
    } else {
        float* cbar = (float*)d_ws;
        hipMemsetAsync(cbar, 0, (size_t)n_vert * sizeof(float), stream);
        scatter_add_dev_kernel<<<4096, TPB, 0, stream>>>(edgeij, edge_attr, cbar,
                                                         (int)(n_edge / 4));
        update_kernel<<<(n_vert + TPB - 1) / TPB, TPB, 0, stream>>>(
            vertex_attr, cbar, g, (float*)d_out, n_vert);
    }
}

// Round 16
// 114.422 us; speedup vs baseline: 1.6259x; 1.0135x over previous
//
#include <hip/hip_runtime.h>

#define TPB    256
#define VSHIFT 12
#define VBUCK  (1 << VSHIFT)        // 4096 vertices per bucket
#define NBMAX  256                  // max buckets (1e6/4096 = 245); == TPB
#define EPT    16                   // edges/thread/round
#define ROUND  (TPB * EPT)          // 4096 edges/round
#define RPB    4                    // rounds per block
#define PBLK   (ROUND * RPB)        // 16384 edges/block
#define SPLITMAX 4                  // accumulate sub-blocks per bucket
#define ATPB   1024                 // accumulate threads per block
#define KDEP   8                    // 16B loads in flight per thread

#define FPSCALE     16777216.0f            // 2^24
#define FPINV       5.9604644775390625e-8f // 2^-24

typedef unsigned uint32x4 __attribute__((ext_vector_type(4)));

__device__ __forceinline__ unsigned long long pack_pair(int d, float v) {
    return (unsigned long long)(unsigned)d |
           ((unsigned long long)__float_as_uint(v) << 32);
}

// Raw 16B global load, NOT waited — caller must s_waitcnt vmcnt(0) before use.
__device__ __forceinline__ uint32x4 gload16_async(const void* p) {
    uint32x4 r;
    asm volatile("global_load_dwordx4 %0, %1, off"
                 : "=&v"(r) : "v"(p));
    return r;
}

// Exclusive scan across TPB threads; also returns block total (uniform).
__device__ __forceinline__ int block_excl_scan(int v, int t, int* wsum, int* total) {
    int s = v;
    #pragma unroll
    for (int d = 1; d < 64; d <<= 1) {
        int u = __shfl_up(s, d);
        if ((t & 63) >= d) s += u;
    }
    if ((t & 63) == 63) wsum[t >> 6] = s;
    __syncthreads();
    int add = 0;
    #pragma unroll
    for (int w = 0; w < TPB / 64; ++w)
        if (w < (t >> 6)) add += wsum[w];
    int tot = wsum[0] + wsum[1] + wsum[2] + wsum[3];
    __syncthreads();                 // wsum safe for reuse
    *total = tot;
    return s + add - v;
}

// Per-ROUND bucket histograms: histp_t[round][t] (coalesced), plus per-block
// totals histp_b[t][blk] for the row scan. Same atomic work as before,
// finer-grained storage — partition no longer recomputes it.
__global__ void hist_rounds_kernel(const int* __restrict__ dst, long long n_edge,
                                   int nblk, int* __restrict__ histp_t,
                                   int* __restrict__ histp_b) {
    __shared__ int h[NBMAX];
    const int t = threadIdx.x;
    const long long bbase = (long long)blockIdx.x * PBLK;
    int total = 0;
    for (int r = 0; r < RPB; ++r) {
        h[t] = 0;
        __syncthreads();
        const long long rbase = bbase + (long long)r * ROUND;
        #pragma unroll
        for (int j = 0; j < EPT / 4; ++j) {
            long long e = rbase + ((long long)j * TPB + t) * 4;
            if (e + 4 <= n_edge) {
                int4 d = *reinterpret_cast<const int4*>(dst + e);
                atomicAdd(&h[d.x >> VSHIFT], 1);
                atomicAdd(&h[d.y >> VSHIFT], 1);
                atomicAdd(&h[d.z >> VSHIFT], 1);
                atomicAdd(&h[d.w >> VSHIFT], 1);
            } else {
                for (int q = 0; q < 4; ++q) {
                    long long ee = e + q;
                    if (ee < n_edge) atomicAdd(&h[dst[ee] >> VSHIFT], 1);
                }
            }
        }
        __syncthreads();
        int hv = h[t];
        histp_t[((size_t)blockIdx.x * RPB + r) * NBMAX + t] = hv;
        total += hv;
        // no extra sync needed: each thread zeroes only its own h[t] next round
    }
    histp_b[(size_t)t * nblk + blockIdx.x] = total;
}

// One block per bucket: exclusive-scan its row of per-block counts in place;
// write the bucket total.
__global__ void row_scan_kernel(int* __restrict__ histp, int nblk,
                                int* __restrict__ totals) {
    __shared__ int wsum[TPB / 64];
    const int t = threadIdx.x;
    int* row = histp + (size_t)blockIdx.x * nblk;
    int carry = 0;
    for (int base = 0; base < nblk; base += TPB) {
        int v = (base + t < nblk) ? row[base + t] : 0;
        int tot;
        int excl = block_excl_scan(v, t, wsum, &tot);
        if (base + t < nblk) row[base + t] = carry + excl;
        carry += tot;
        __syncthreads();
    }
    if (t == 0) totals[blockIdx.x] = carry;
}

// Exclusive scan of bucket totals -> bucket base offsets (base[NBMAX+1]).
__global__ void base_scan_kernel(const int* __restrict__ totals, int nb,
                                 int* __restrict__ base) {
    __shared__ int wsum[TPB / 64];
    const int t = threadIdx.x;
    int v = (t < nb) ? totals[t] : 0;
    int tot;
    int excl = block_excl_scan(v, t, wsum, &tot);
    base[t] = excl;
    if (t == TPB - 1) base[TPB] = excl + v;
}

// Partition: offsets AND per-round histograms fully precomputed. Per round:
// read h[t] (prefetched), wave-scan, scatter into sorted LDS stage, flush.
// 3 LDS ops/edge, 4 barriers/round (was 4 ops, 6 barriers).
__global__ __launch_bounds__(TPB, 4)
void partition_kernel(const int* __restrict__ dst,
                      const float* __restrict__ ea,
                      long long n_edge, int nblk,
                      const int* __restrict__ histp_t,
                      const int* __restrict__ histp_b,
                      const int* __restrict__ base,
                      unsigned long long* __restrict__ pairs) {
    __shared__ unsigned long long stage[ROUND];   // 32 KB, bucket-sorted pairs
    __shared__ int pos[NBMAX];    // round scatter cursors
    __shared__ int adj[NBMAX];    // gbase - pfx per bucket
    __shared__ int wsum[TPB / 64];

    const int t = threadIdx.x;
    const long long bbase = (long long)blockIdx.x * PBLK;
    int my_gbase = base[t] + histp_b[(size_t)t * nblk + blockIdx.x];

    // prefetch all RPB per-round counts for this block (coalesced)
    int hv[RPB];
    #pragma unroll
    for (int r = 0; r < RPB; ++r)
        hv[r] = histp_t[((size_t)blockIdx.x * RPB + r) * NBMAX + t];

    if (bbase + PBLK <= n_edge) {
        // ---------- fast path: full block, prefetch double-buffer ----------
        int4   dr[2][EPT / 4];
        float4 vr[2][EPT / 4];
        #pragma unroll
        for (int j = 0; j < EPT / 4; ++j) {
            long long e = bbase + ((long long)j * TPB + t) * 4;
            dr[0][j] = *reinterpret_cast<const int4*>(dst + e);
            vr[0][j] = *reinterpret_cast<const float4*>(ea + e);
        }
        #pragma unroll
        for (int r = 0; r < RPB; ++r) {
            const int cur = r & 1, nxt = cur ^ 1;
            if (r + 1 < RPB) {                    // issue next round's loads NOW
                const long long pb = bbase + (long long)(r + 1) * ROUND;
                #pragma unroll
                for (int j = 0; j < EPT / 4; ++j) {
                    long long e = pb + ((long long)j * TPB + t) * 4;
                    dr[nxt][j] = *reinterpret_cast<const int4*>(dst + e);
                    vr[nxt][j] = *reinterpret_cast<const float4*>(ea + e);
                }
            }
            int rt;
            int excl = block_excl_scan(hv[r], t, wsum, &rt);   // 2 syncs
            pos[t] = excl;
            adj[t] = my_gbase - excl;
            __syncthreads();
            #pragma unroll
            for (int j = 0; j < EPT / 4; ++j) {
                int   dd[4] = {dr[cur][j].x, dr[cur][j].y, dr[cur][j].z, dr[cur][j].w};
                float vv[4] = {vr[cur][j].x, vr[cur][j].y, vr[cur][j].z, vr[cur][j].w};
                #pragma unroll
                for (int q = 0; q < 4; ++q) {
                    int b = dd[q] >> VSHIFT;
                    int slot = atomicAdd(&pos[b], 1);
                    stage[slot] = pack_pair(dd[q], vv[q]);
                }
            }
            __syncthreads();
            #pragma unroll
            for (int i0 = 0; i0 < ROUND; i0 += TPB) {
                int i = i0 + t;
                unsigned long long p = stage[i];
                int b = (int)((unsigned)(p & 0xffffffffull) >> VSHIFT);
                pairs[(size_t)(adj[b] + i)] = p;
            }
            my_gbase += hv[r];
            // next round's scan 1st sync protects stage/adj reuse
        }
    } else {
        // ---------- guarded tail path (last block only) ----------
        const long long bend = n_edge;
        for (int r = 0; r < RPB; ++r) {
            const long long rbase = bbase + (long long)r * ROUND;
            if (rbase >= bend) break;              // uniform across block

            int4   dreg[EPT / 4];
            float4 vreg[EPT / 4];
            int    nval[EPT / 4];
            #pragma unroll
            for (int j = 0; j < EPT / 4; ++j) {
                long long e = rbase + ((long long)j * TPB + t) * 4;
                if (e + 4 <= bend) {
                    dreg[j] = *reinterpret_cast<const int4*>(dst + e);
                    vreg[j] = *reinterpret_cast<const float4*>(ea + e);
                    nval[j] = 4;
                } else {
                    int dd[4] = {0, 0, 0, 0};
                    float vv[4] = {0.f, 0.f, 0.f, 0.f};
                    int nv = 0;
                    for (int q = 0; q < 4; ++q) {
                        long long ee = e + q;
                        if (ee < bend) { dd[q] = dst[ee]; vv[q] = ea[ee]; nv = q + 1; }
                    }
                    dreg[j] = make_int4(dd[0], dd[1], dd[2], dd[3]);
                    vreg[j] = make_float4(vv[0], vv[1], vv[2], vv[3]);
                    nval[j] = nv;
                }
            }

            int rt;
            int excl = block_excl_scan(hv[r], t, wsum, &rt);
            pos[t] = excl;
            adj[t] = my_gbase - excl;
            __syncthreads();

            #pragma unroll
            for (int j = 0; j < EPT / 4; ++j) {
                int   dd[4] = {dreg[j].x, dreg[j].y, dreg[j].z, dreg[j].w};
                float vv[4] = {vreg[j].x, vreg[j].y, vreg[j].z, vreg[j].w};
                #pragma unroll
                for (int q = 0; q < 4; ++q) {
                    if (q < nval[j]) {
                        int b = dd[q] >> VSHIFT;
                        int slot = atomicAdd(&pos[b], 1);
                        stage[slot] = pack_pair(dd[q], vv[q]);
                    }
                }
            }
            __syncthreads();

            for (int i = t; i < rt; i += TPB) {
                unsigned long long p = stage[i];
                int b = (int)((unsigned)(p & 0xffffffffull) >> VSHIFT);
                pairs[(size_t)(adj[b] + i)] = p;
            }
            __syncthreads();
            my_gbase += hv[r];
        }
    }
}

// split blocks per bucket: int fixed-point LDS accumulate (fast ds_add_u32),
// KDEP-deep asm-batched loads. Converted back to float on writeback.
__global__ __launch_bounds__(ATPB)
void accum_partial_kernel(const unsigned long long* pairs,
                          const int* __restrict__ base,
                          float* __restrict__ partials, int n_vert, int nb,
                          int split) {
    __shared__ __align__(16) int acc[VBUCK];
    const int b  = blockIdx.x % nb;
    const int sp = blockIdx.x / nb;
    const int t  = threadIdx.x;
    #pragma unroll
    for (int i = t; i < VBUCK; i += ATPB) acc[i] = 0;
    __syncthreads();

    const int s = base[b];
    const int e = base[b + 1];
    const long long len = e - s;
    const int i0 = s + (int)((len * sp) / split);
    const int i1 = s + (int)((len * (sp + 1)) / split);
    const int a0 = (i0 + 1) & ~1;          // first even index >= i0
    const int a1 = i1 & ~1;                // last even boundary <= i1

    if (t == 0 && (i0 & 1) && i0 < i1) {
        unsigned long long p = pairs[i0];
        atomicAdd(&acc[(int)(p & (VBUCK - 1))],
                  __float2int_rn(__uint_as_float((unsigned)(p >> 32)) * FPSCALE));
    }
    if (t == 1 && (i1 & 1) && (i1 - 1) >= i0) {
        unsigned long long p = pairs[i1 - 1];
        atomicAdd(&acc[(int)(p & (VBUCK - 1))],
                  __float2int_rn(__uint_as_float((unsigned)(p >> 32)) * FPSCALE));
    }

    const int n2 = (a1 - a0) >> 1;         // 16B (2-pair) elements
    if (n2 > 0) {
        const char* pv = reinterpret_cast<const char*>(pairs + a0);
        const int nm1 = n2 - 1;
        for (int bb = 0; bb < n2; bb += KDEP * ATPB) {
            uint32x4 q[KDEP];
            int idx[KDEP];
            #pragma unroll
            for (int k = 0; k < KDEP; ++k) {
                idx[k] = bb + t + k * ATPB;
                int ci = idx[k] < nm1 ? idx[k] : nm1;
                q[k] = gload16_async(pv + (size_t)ci * 16);
            }
            asm volatile("s_waitcnt vmcnt(0)" ::: "memory");
            __builtin_amdgcn_sched_barrier(0);
            #pragma unroll
            for (int k = 0; k < KDEP; ++k) {
                if (idx[k] < n2) {
                    atomicAdd(&acc[(int)(q[k][0] & (VBUCK - 1))],
                              __float2int_rn(__uint_as_float(q[k][1]) * FPSCALE));
                    atomicAdd(&acc[(int)(q[k][2] & (VBUCK - 1))],
                              __float2int_rn(__uint_as_float(q[k][3]) * FPSCALE));
                }
            }
        }
    }
    __syncthreads();

    float* pp = partials + (size_t)sp * n_vert;
    const int vbase = b << VSHIFT;
    if (vbase + VBUCK <= n_vert) {
        int4 a = reinterpret_cast<const int4*>(acc)[t];
        float4 f;
        f.x = (float)a.x * FPINV; f.y = (float)a.y * FPINV;
        f.z = (float)a.z * FPINV; f.w = (float)a.w * FPINV;
        reinterpret_cast<float4*>(pp + vbase)[t] = f;
    } else {
        for (int v = t; vbase + v < n_vert; v += ATPB)
            pp[vbase + v] = (float)acc[v] * FPINV;
    }
}

// Sum split partials + vertex update; 4 vertices/thread, float4 I/O.
__global__ void final_update_kernel(const float* __restrict__ partials,
                                    const float* __restrict__ va,
                                    const float* __restrict__ g,
                                    float* __restrict__ out, int n_vert,
                                    int split) {
    const int gt = blockIdx.x * blockDim.x + threadIdx.x;
    const float w = g[0];
    const int v0 = gt * 4;
    if (v0 + 4 <= n_vert) {
        float4 c = reinterpret_cast<const float4*>(partials)[gt];
        for (int sp = 1; sp < split; ++sp) {
            float4 c2 = reinterpret_cast<const float4*>(
                            partials + (size_t)sp * n_vert)[gt];
            c.x += c2.x; c.y += c2.y; c.z += c2.z; c.w += c2.w;
        }
        float4 f0 = reinterpret_cast<const float4*>(va)[gt * 3 + 0];
        float4 f1 = reinterpret_cast<const float4*>(va)[gt * 3 + 1];
        float4 f2 = reinterpret_cast<const float4*>(va)[gt * 3 + 2];
        float4 o0, o1, o2;
        o0.x = f0.x; o0.y = f0.y; o0.z = f0.z + w * (f0.y - c.x) / f0.x;
        o0.w = f0.w; o1.x = f1.x; o1.y = f1.y + w * (f1.x - c.y) / f0.w;
        o1.z = f1.z; o1.w = f1.w; o2.x = f2.x + w * (f1.w - c.z) / f1.z;
        o2.y = f2.y; o2.z = f2.z; o2.w = f2.w + w * (f2.z - c.w) / f2.y;
        reinterpret_cast<float4*>(out)[gt * 3 + 0] = o0;
        reinterpret_cast<float4*>(out)[gt * 3 + 1] = o1;
        reinterpret_cast<float4*>(out)[gt * 3 + 2] = o2;
    } else {
        for (int i = v0; i < n_vert; ++i) {
            float c = 0.f;
            for (int sp = 0; sp < split; ++sp)
                c += partials[(size_t)sp * n_vert + i];
            float A = va[3 * i], bb = va[3 * i + 1], x = va[3 * i + 2];
            out[3 * i]     = A;
            out[3 * i + 1] = bb;
            out[3 * i + 2] = x + w * (bb - c) / A;
        }
    }
}

// Fused path (used if partials don't fit in ws) — int fixed-point accumulate.
__global__ void accum_update_kernel(const unsigned long long* __restrict__ pairs,
                                    const int* __restrict__ base,
                                    const float* __restrict__ va,
                                    const float* __restrict__ g,
                                    float* __restrict__ out, int n_vert) {
    __shared__ __align__(16) int acc[VBUCK];
    const int b = blockIdx.x;
    const int T = blockDim.x;                  // 1024
    for (int t = threadIdx.x; t < VBUCK; t += T) acc[t] = 0;
    __syncthreads();
    const int s = base[b];
    const int e = base[b + 1];
    for (int i = s + threadIdx.x; i < e; i += T) {
        unsigned long long p = pairs[i];
        atomicAdd(&acc[(int)(p & (VBUCK - 1))],
                  __float2int_rn(__uint_as_float((unsigned)(p >> 32)) * FPSCALE));
    }
    __syncthreads();

    const float w = g[0];
    const int vbase = b << VSHIFT;
    const int t = threadIdx.x;
    const int v0 = vbase + t * 4;
    if (v0 + 4 <= n_vert) {
        const int gt = v0 >> 2;
        float4 f0 = reinterpret_cast<const float4*>(va)[gt * 3 + 0];
        float4 f1 = reinterpret_cast<const float4*>(va)[gt * 3 + 1];
        float4 f2 = reinterpret_cast<const float4*>(va)[gt * 3 + 2];
        int4   a  = reinterpret_cast<const int4*>(acc)[t];
        float4 c;
        c.x = (float)a.x * FPINV; c.y = (float)a.y * FPINV;
        c.z = (float)a.z * FPINV; c.w = (float)a.w * FPINV;
        float4 o0, o1, o2;
        o0.x = f0.x; o0.y = f0.y; o0.z = f0.z + w * (f0.y - c.x) / f0.x;
        o0.w = f0.w; o1.x = f1.x; o1.y = f1.y + w * (f1.x - c.y) / f0.w;
        o1.z = f1.z; o1.w = f1.w; o2.x = f2.x + w * (f1.w - c.z) / f1.z;
        o2.y = f2.y; o2.z = f2.z; o2.w = f2.w + w * (f2.z - c.w) / f2.y;
        reinterpret_cast<float4*>(out)[gt * 3 + 0] = o0;
        reinterpret_cast<float4*>(out)[gt * 3 + 1] = o1;
        reinterpret_cast<float4*>(out)[gt * 3 + 2] = o2;
    } else {
        for (int i = v0; i < n_vert && i < v0 + 4; ++i) {
            float A = va[3 * i], bb = va[3 * i + 1], x = va[3 * i + 2];
            out[3 * i]     = A;
            out[3 * i + 1] = bb;
            out[3 * i + 2] = x + w * (bb - (float)acc[i - vbase] * FPINV) / A;
        }
    }
}

// ---- fallback path (insufficient scratch): device-scope atomics ----
__global__ void scatter_add_dev_kernel(const int* __restrict__ dst,
                                       const float* __restrict__ ea,
                                       float* __restrict__ acc, int n_edges4) {
    int i = blockIdx.x * blockDim.x + threadIdx.x;
    const int stride = gridDim.x * blockDim.x;
    for (; i < n_edges4; i += stride) {
        int4   d = reinterpret_cast<const int4*>(dst)[i];
        float4 v = reinterpret_cast<const float4*>(ea)[i];
        atomicAdd(&acc[d.x], v.x);
        atomicAdd(&acc[d.y], v.y);
        atomicAdd(&acc[d.z], v.z);
        atomicAdd(&acc[d.w], v.w);
    }
}

__global__ void update_kernel(const float* __restrict__ va,
                              const float* __restrict__ cbar,
                              const float* __restrict__ g,
                              float* __restrict__ out, int n) {
    int i = blockIdx.x * blockDim.x + threadIdx.x;
    if (i >= n) return;
    float A = va[3 * i], b = va[3 * i + 1], x = va[3 * i + 2];
    out[3 * i]     = A;
    out[3 * i + 1] = b;
    out[3 * i + 2] = x + g[0] * (b - cbar[i]) / A;
}

extern "C" void kernel_launch(void* const* d_in, const int* in_sizes, int n_in,
                              void* d_out, int out_size, void* d_ws, size_t ws_size,
                              hipStream_t stream) {
    const float* vertex_attr = (const float*)d_in[0];
    const int*   edgeij      = (const int*)d_in[1];   // row 0 = dst
    const float* edge_attr   = (const float*)d_in[2];
    const float* g           = (const float*)d_in[3];

    const int       n_vert = in_sizes[0] / 3;
    const long long n_edge = in_sizes[2];
    const int       nb     = (n_vert + VBUCK - 1) >> VSHIFT;
    const int       nblk   = (int)((n_edge + PBLK - 1) / PBLK);

    // ws layout: [histp_t][histp_b][totals][base][pairs][partials (optional)]
    size_t histt_sz   = (size_t)nblk * RPB * NBMAX * sizeof(int);   // 4 MB
    size_t histb_off  = (histt_sz + 255) & ~(size_t)255;
    size_t histb_sz   = (size_t)NBMAX * nblk * sizeof(int);         // 1 MB
    size_t totals_off = (histb_off + histb_sz + 255) & ~(size_t)255;
    size_t base_off   = totals_off + NBMAX * sizeof(int);
    size_t pairs_off  = (base_off + (TPB + 1) * sizeof(int) + 255) & ~(size_t)255;
    size_t need1      = pairs_off + (size_t)n_edge * sizeof(unsigned long long);
    size_t part_off   = (need1 + 255) & ~(size_t)255;

    if (ws_size >= need1 && nb <= NBMAX) {
        int* histp_t = (int*)d_ws;
        int* histp_b = (int*)((char*)d_ws + histb_off);
        int* totals  = (int*)((char*)d_ws + totals_off);
        int* basep   = (int*)((char*)d_ws + base_off);
        unsigned long long* pairs =
            (unsigned long long*)((char*)d_ws + pairs_off);

        hist_rounds_kernel<<<nblk, TPB, 0, stream>>>(edgeij, n_edge, nblk,
                                                     histp_t, histp_b);
        row_scan_kernel<<<nb, TPB, 0, stream>>>(histp_b, nblk, totals);
        base_scan_kernel<<<1, TPB, 0, stream>>>(totals, nb, basep);
        partition_kernel<<<nblk, TPB, 0, stream>>>(edgeij, edge_attr, n_edge,
                                                   nblk, histp_t, histp_b,
                                                   basep, pairs);

        // pick largest split whose partials fit in remaining ws
        int split = 0;
        for (int sp = SPLITMAX; sp >= 2; sp >>= 1) {
            if (ws_size >= part_off + (size_t)sp * n_vert * sizeof(float)) {
                split = sp; break;
            }
        }
        if (split) {
            float* partials = (float*)((char*)d_ws + part_off);
            accum_partial_kernel<<<nb * split, ATPB, 0, stream>>>(
                pairs, basep, partials, n_vert, nb, split);
            const int uthreads = (n_vert + 3) / 4;
            final_update_kernel<<<(uthreads + TPB - 1) / TPB, TPB, 0, stream>>>(
                partials, vertex_attr, g, (float*)d_out, n_vert, split);
        } else {
            accum_update_kernel<<<nb, 1024, 0, stream>>>(pairs, basep, vertex_attr,
                                                         g, (float*)d_out, n_vert);
        }
    } else {
        float* cbar = (float*)d_ws;
        hipMemsetAsync(cbar, 0, (size_t)n_vert * sizeof(float), stream);
        scatter_add_dev_kernel<<<4096, TPB, 0, stream>>>(edgeij, edge_attr, cbar,
                                                         (int)(n_edge / 4));
        update_kernel<<<(n_vert + TPB - 1) / TPB, TPB, 0, stream>>>(
            vertex_attr, cbar, g, (float*)d_out, n_vert);
    }
}